// Round 4
// baseline (304.511 us; speedup 1.0000x reference)
//
#include <hip/hip_runtime.h>

typedef unsigned long long ull;

#define NA 147456
#define NB 16
#define NBINS 16384        // top-14 bits of monotonic key
#define CAND_CAP 2048
#define NPOST 1000

// ws layout (bytes)
#define OFF_CAND    0                    // 16*2048*8      = 262144
#define OFF_MASK    262144               // 16*1000*16*8   = 2048000
#define OFF_HIST    2310144              // 16*16384*4     = 1048576
#define OFF_PART    3358720              // 16*16*8        = 2048
#define OFF_META    3360768              // 16*16          = 256
#define OFF_CNT     3361024              // 16*4           = 64
#define OFF_SBOX    3361088              // 16*1000*16     = 256000
#define OFF_SSCORE  3617088              // 16*1000*4      = 64000

__device__ __forceinline__ unsigned mkey(float f) {
  unsigned u = __float_as_uint(f);
  return u ^ ((unsigned)((int)u >> 31) | 0x80000000u);  // monotonic: bigger float -> bigger key
}

__device__ __forceinline__ ull readlane64(ull v, int lane) {
  unsigned lo = (unsigned)__builtin_amdgcn_readlane((int)(unsigned)(v & 0xFFFFFFFFu), lane);
  unsigned hi = (unsigned)__builtin_amdgcn_readlane((int)(unsigned)(v >> 32), lane);
  return ((ull)hi << 32) | lo;
}

// ---------------- K0: zero hist + candidate counters (ws is poisoned 0xAA) ----
__global__ void k_init(unsigned* hist, unsigned* cnt) {
  int n = NB * NBINS;
  for (int i = blockIdx.x * blockDim.x + threadIdx.x; i < n; i += gridDim.x * blockDim.x)
    hist[i] = 0;
  if (blockIdx.x == 0 && threadIdx.x < NB) cnt[threadIdx.x] = 0;
}

// ---------------- K1: fused online softmax-reduce + 14-bit histogram ---------
__global__ __launch_bounds__(256) void k_reduce_hist(const float* __restrict__ labels,
                                                     unsigned* __restrict__ hist,
                                                     float2* __restrict__ partial) {
  int b = blockIdx.x >> 4, blk = blockIdx.x & 15;
  __shared__ unsigned lh[NBINS];           // 64KB
  __shared__ float rm[256], rs[256];
  for (int i = threadIdx.x; i < NBINS; i += 256) lh[i] = 0;
  __syncthreads();

  const float* row = labels + (size_t)b * NA;
  const int chunk = NA / 16;               // 9216, divisible by 256
  int base = blk * chunk;
  float m = -INFINITY, s = 0.f;
  for (int i = threadIdx.x; i < chunk; i += 256) {
    float v = row[base + i];
    atomicAdd(&lh[mkey(v) >> 18], 1u);
    if (v > m) { s = s * expf(m - v) + 1.f; m = v; }
    else       { s += expf(v - m); }
  }
  rm[threadIdx.x] = m; rs[threadIdx.x] = s;
  __syncthreads();
  for (int off = 128; off > 0; off >>= 1) {
    if (threadIdx.x < off) {
      float m1 = rm[threadIdx.x], s1 = rs[threadIdx.x];
      float m2 = rm[threadIdx.x + off], s2 = rs[threadIdx.x + off];
      float M = fmaxf(m1, m2);
      rm[threadIdx.x] = M;
      rs[threadIdx.x] = s1 * expf(m1 - M) + s2 * expf(m2 - M);
    }
    __syncthreads();
  }
  if (threadIdx.x == 0) partial[blockIdx.x] = make_float2(rm[0], rs[0]);
  for (int i = threadIdx.x; i < NBINS; i += 256) {
    unsigned c = lh[i];
    if (c) atomicAdd(&hist[b * NBINS + i], c);
  }
}

// ---------------- K2: finalize (m,S), find threshold bin ---------------------
__global__ __launch_bounds__(1024) void k_threshold(const unsigned* __restrict__ hist,
                                                    const float2* __restrict__ partial,
                                                    float4* __restrict__ meta) {
  int b = blockIdx.x;
  __shared__ float red_m, red_s;
  __shared__ unsigned cs[1024];
  if (threadIdx.x == 0) {
    float m = -INFINITY, s = 0.f;
    for (int i = 0; i < 16; ++i) {
      float2 p = partial[b * 16 + i];
      float M = fmaxf(m, p.x);
      s = s * expf(m - M) + p.y * expf(p.x - M);
      m = M;
    }
    red_m = m; red_s = s;
  }
  const unsigned* h = hist + (size_t)b * NBINS;
  int t = threadIdx.x;
  unsigned local[16], lsum = 0;
  for (int q = 0; q < 16; ++q) {            // rank r = t*16+q, bin = NBINS-1-r (scan from top)
    local[q] = h[NBINS - 1 - (t * 16 + q)];
    lsum += local[q];
  }
  cs[t] = lsum;
  __syncthreads();
  for (int off = 1; off < 1024; off <<= 1) {  // Hillis-Steele inclusive scan
    unsigned v = (t >= off) ? cs[t - off] : 0u;
    __syncthreads();
    cs[t] += v;
    __syncthreads();
  }
  unsigned incl = cs[t], excl = incl - lsum;
  if (excl < NPOST && incl >= NPOST) {
    unsigned running = excl;
    for (int q = 0; q < 16; ++q) {
      unsigned c = local[q];
      if (running < NPOST && running + c >= NPOST) {
        unsigned bin = NBINS - 1 - (t * 16 + q);
        meta[b] = make_float4(red_m, red_s, __uint_as_float(bin), 0.f);
      }
      running += c;
    }
  }
}

// ---------------- K3: compact candidates >= threshold bin --------------------
// Two-phase: (1) all 9 float4 loads issued upfront into registers (one
// latency), (2) ballot-aggregated compaction -- zero-ballot groups (the
// overwhelming majority) cost ~3 instructions and no atomics.
__global__ __launch_bounds__(256) void k_compact(const float* __restrict__ labels,
                                                 const float4* __restrict__ meta,
                                                 ull* __restrict__ cand,
                                                 unsigned* __restrict__ cnt) {
  int b = blockIdx.x >> 4, blk = blockIdx.x & 15;
  unsigned tb = __float_as_uint(meta[b].z);
  const int chunk = NA / 16;               // 9216 floats = 2304 float4
  const float4* row4 = (const float4*)(labels + (size_t)b * NA + blk * chunk);
  int lane = threadIdx.x & 63;

  float4 v[9];
#pragma unroll
  for (int it = 0; it < 9; ++it)
    v[it] = row4[it * 256 + threadIdx.x];

  ull* cb = cand + (size_t)b * CAND_CAP;
#pragma unroll
  for (int it = 0; it < 9; ++it) {
    unsigned k0 = mkey(v[it].x), k1 = mkey(v[it].y);
    unsigned k2 = mkey(v[it].z), k3 = mkey(v[it].w);
    int base_idx = blk * chunk + (it * 256 + threadIdx.x) * 4;
#pragma unroll
    for (int j = 0; j < 4; ++j) {
      unsigned kk = (j == 0) ? k0 : (j == 1) ? k1 : (j == 2) ? k2 : k3;
      bool pred = (kk >> 18) >= tb;
      ull mball = __ballot(pred);
      if (mball) {
        unsigned base = 0;
        if (lane == 0) base = atomicAdd(&cnt[b], (unsigned)__popcll(mball));
        base = (unsigned)__builtin_amdgcn_readfirstlane((int)base);
        if (pred) {
          unsigned rank = (unsigned)__popcll(mball & ((1ull << lane) - 1ull));
          unsigned p = base + rank;
          unsigned idx = (unsigned)(base_idx + j);
          if (p < CAND_CAP) cb[p] = ((ull)kk << 32) | (unsigned)~idx;
        }
      }
    }
  }
}

// ---------------- K4: bitonic sort candidates, emit top-1000 boxes/scores ----
__global__ __launch_bounds__(1024) void k_sort_emit(const ull* __restrict__ cand,
                                                    const unsigned* __restrict__ cnt,
                                                    const float4* __restrict__ meta,
                                                    const float* __restrict__ labels,
                                                    const float* __restrict__ deltas,
                                                    const float4* __restrict__ anchors,
                                                    const float* __restrict__ variances,
                                                    float4* __restrict__ sboxes,
                                                    float* __restrict__ sscores) {
  int b = blockIdx.x;
  __shared__ ull sd[CAND_CAP];
  unsigned n = cnt[b]; if (n > CAND_CAP) n = CAND_CAP;
  for (int i = threadIdx.x; i < CAND_CAP; i += 1024)
    sd[i] = (i < (int)n) ? cand[(size_t)b * CAND_CAP + i] : 0ULL;

  // bitonic sort, descending (key desc, index asc via ~idx in low bits)
  for (int k = 2; k <= CAND_CAP; k <<= 1) {
    for (int j = k >> 1; j > 0; j >>= 1) {
      __syncthreads();
      for (int e = threadIdx.x; e < CAND_CAP; e += 1024) {
        int x = e ^ j;
        if (x > e) {
          ull a = sd[e], c = sd[x];
          bool up = (e & k) == 0;
          if (up ? (a < c) : (a > c)) { sd[e] = c; sd[x] = a; }
        }
      }
    }
  }
  __syncthreads();

  int r = threadIdx.x;
  if (r < NPOST) {
    ull en = sd[r];
    unsigned idx = ~(unsigned)(en & 0xFFFFFFFFu);
    float4 mt = meta[b];
    float lab = labels[(size_t)b * NA + idx];
    float score = expf(lab - mt.x) / mt.y;

    float4 an = anchors[idx];                     // [y1,x1,y2,x2]
    float aw = an.w - an.y;
    float ah = an.z - an.x;
    float acx = an.y + 0.5f * aw;
    float acy = an.x + 0.5f * ah;
    float4 dl = *(const float4*)(deltas + ((size_t)b * NA + idx) * 4);
    float4 var = *(const float4*)variances;
    float t0 = dl.x * var.x, t1 = dl.y * var.y, t2 = dl.z * var.z, t3 = dl.w * var.w;
    float bw = expf(t3) * aw;
    float bh = expf(t2) * ah;
    float bcx = t1 * aw + acx;
    float bcy = t0 * ah + acy;
    float y1 = bcy - 0.5f * bh, x1 = bcx - 0.5f * bw;
    float y2 = bh + y1, x2 = bw + x1;
    sboxes[(size_t)b * NPOST + r] = make_float4(y1, x1, y2, x2);
    sscores[(size_t)b * NPOST + r] = score;
  }
}

// ---------------- K5: pairwise IoU suppression bitmask -----------------------
__global__ __launch_bounds__(256) void k_mask(const float4* __restrict__ sboxes,
                                              ull* __restrict__ mask) {
  int b = blockIdx.x / 63, tile = blockIdx.x % 63;
  __shared__ float4 bx[NPOST];               // 16KB
  for (int j = threadIdx.x; j < NPOST; j += 256) bx[j] = sboxes[(size_t)b * NPOST + j];
  __syncthreads();
  int il = threadIdx.x >> 4, w = threadIdx.x & 15;
  int i = tile * 16 + il;
  if (i < NPOST) {
    float4 bi = bx[i];
    float ay1 = bi.x, ax1 = bi.y, ay2 = bi.z, ax2 = bi.w;
    float areai = (ay2 - ay1) * (ax2 - ax1);
    ull bits = 0;
    for (int jj = 0; jj < 64; ++jj) {
      int jb = (jj + w) & 63;                // skew to dodge LDS bank conflicts
      int j = (w << 6) + jb;
      if (j > i && j < NPOST) {
        float4 bj = bx[j];
        float areaj = (bj.z - bj.x) * (bj.w - bj.y);
        float iy1 = fmaxf(ay1, bj.x), ix1 = fmaxf(ax1, bj.y);
        float iy2 = fminf(ay2, bj.z), ix2 = fminf(ax2, bj.w);
        float inter = fmaxf(iy2 - iy1, 0.f) * fmaxf(ix2 - ix1, 0.f);
        float uni = areai + areaj - inter;
        float iou = inter / fmaxf(uni, 1e-9f);
        if (iou > 0.7f) bits |= (1ull << jb);
      }
    }
    mask[((size_t)b * NPOST + i) * 16 + w] = bits;
  }
}

// ---------------- K6: serial greedy NMS, shfl-free chain ---------------------
__global__ __launch_bounds__(256) void k_nms(const ull* __restrict__ mask,
                                             const float4* __restrict__ sboxes,
                                             const float* __restrict__ sscores,
                                             float* __restrict__ out) {
  int b = blockIdx.x;
  __shared__ ull keepw[16];
  __shared__ int pref[17];
  int tid = threadIdx.x;

  if (tid < 64) {
    int lane = tid;
    const ull* Mrow = mask + (size_t)b * NPOST * 16;
    int wsel = lane & 15;
    ull vremv = 0;
    ull buf[32];                             // 32-deep static prefetch ring
#pragma unroll
    for (int d = 0; d < 32; ++d)
      buf[d] = Mrow[(size_t)d * 16 + wsel];

#pragma unroll 1
    for (int w = 0; w < 16; ++w) {
      ull rm = readlane64(vremv, w);
#pragma unroll 1
      for (int b0 = 0; b0 < 64; b0 += 32) {
#pragma unroll
        for (int d = 0; d < 32; ++d) {
          int t = w * 64 + b0 + d;           // scan index (padded to 1024)
          ull cur = buf[d];
          int nx = t + 32;
          int rc = nx < NPOST ? nx : NPOST - 1;  // row 999's mask row is all-zero
          buf[d] = Mrow[(size_t)rc * 16 + wsel];
          int bit = b0 + d;
          if (!((rm >> bit) & 1ull)) {
            vremv |= cur;
            rm = readlane64(vremv, w);
          }
        }
      }
      if (lane == 0) keepw[w] = (w == 15) ? (~rm & ((1ull << 40) - 1)) : ~rm;
    }
    if (lane == 0) {
      int a = 0;
      for (int w = 0; w < 16; ++w) { pref[w] = a; a += __popcll(keepw[w]); }
      pref[16] = a;
    }
  }
  __syncthreads();

  int total = pref[16];
  float4* ob = (float4*)out;                 // boxes: 16*1000 float4
  float* os = out + (size_t)NB * NPOST * 4;  // scores: 16*1000 floats
  for (int r = tid; r < NPOST; r += 256) {
    if (r >= total) {
      ob[(size_t)b * NPOST + r] = make_float4(0.f, 0.f, 0.f, 0.f);
      os[(size_t)b * NPOST + r] = 0.f;
    }
  }
  for (int r = tid; r < NPOST; r += 256) {
    int w = r >> 6, bb = r & 63;
    ull kw = keepw[w];
    if ((kw >> bb) & 1ull) {
      int pos = pref[w] + __popcll(bb ? (kw & ((1ull << bb) - 1)) : 0ull);
      ob[(size_t)b * NPOST + pos] = sboxes[(size_t)b * NPOST + r];
      os[(size_t)b * NPOST + pos] = sscores[(size_t)b * NPOST + r];
    }
  }
}

extern "C" void kernel_launch(void* const* d_in, const int* in_sizes, int n_in,
                              void* d_out, int out_size, void* d_ws, size_t ws_size,
                              hipStream_t stream) {
  const float* deltas    = (const float*)d_in[0];
  const float* labels    = (const float*)d_in[1];
  const float* anchors   = (const float*)d_in[2];
  const float* variances = (const float*)d_in[3];

  char* ws = (char*)d_ws;
  ull*      cand    = (ull*)(ws + OFF_CAND);
  ull*      mask    = (ull*)(ws + OFF_MASK);
  unsigned* hist    = (unsigned*)(ws + OFF_HIST);
  float2*   partial = (float2*)(ws + OFF_PART);
  float4*   meta    = (float4*)(ws + OFF_META);
  unsigned* cnt     = (unsigned*)(ws + OFF_CNT);
  float4*   sboxes  = (float4*)(ws + OFF_SBOX);
  float*    sscores = (float*)(ws + OFF_SSCORE);

  k_init<<<256, 256, 0, stream>>>(hist, cnt);
  k_reduce_hist<<<NB * 16, 256, 0, stream>>>(labels, hist, partial);
  k_threshold<<<NB, 1024, 0, stream>>>(hist, partial, meta);
  k_compact<<<NB * 16, 256, 0, stream>>>(labels, meta, cand, cnt);
  k_sort_emit<<<NB, 1024, 0, stream>>>(cand, cnt, meta, labels, deltas,
                                       (const float4*)anchors, variances,
                                       sboxes, sscores);
  k_mask<<<NB * 63, 256, 0, stream>>>(sboxes, mask);
  k_nms<<<NB, 256, 0, stream>>>(mask, sboxes, sscores, (float*)d_out);
}

// Round 5
// 145.800 us; speedup vs baseline: 2.0886x; 2.0886x over previous
//
#include <hip/hip_runtime.h>

typedef unsigned long long ull;

#define NA 147456
#define NB 16
#define NBINS 16384        // top-14 bits of monotonic key
#define CAND_CAP 2048
#define SEG 128            // CAND_CAP / 16 chunks
#define NPOST 1000

// ws layout (bytes)
#define OFF_CAND    0                    // 16*2048*8      = 262144
#define OFF_MASK    262144               // 16*1000*16*8   = 2048000
#define OFF_HIST    2310144              // 16*16384*4     = 1048576
#define OFF_PART    3358720              // 16*16*8        = 2048
#define OFF_META    3360768              // 16*16          = 256
#define OFF_CNT     3361024              // (unused now)
#define OFF_SBOX    3361088              // 16*1000*16     = 256000
#define OFF_SSCORE  3617088              // 16*1000*4      = 64000

__device__ __forceinline__ unsigned mkey(float f) {
  unsigned u = __float_as_uint(f);
  return u ^ ((unsigned)((int)u >> 31) | 0x80000000u);  // monotonic: bigger float -> bigger key
}

__device__ __forceinline__ ull readlane64(ull v, int lane) {
  unsigned lo = (unsigned)__builtin_amdgcn_readlane((int)(unsigned)(v & 0xFFFFFFFFu), lane);
  unsigned hi = (unsigned)__builtin_amdgcn_readlane((int)(unsigned)(v >> 32), lane);
  return ((ull)hi << 32) | lo;
}

// ---------------- K0: zero hist (ws is poisoned 0xAA) ------------------------
__global__ void k_init(unsigned* hist) {
  int n = NB * NBINS;
  for (int i = blockIdx.x * blockDim.x + threadIdx.x; i < n; i += gridDim.x * blockDim.x)
    hist[i] = 0;
}

// ---------------- K1: fused online softmax-reduce + 14-bit histogram ---------
__global__ __launch_bounds__(256) void k_reduce_hist(const float* __restrict__ labels,
                                                     unsigned* __restrict__ hist,
                                                     float2* __restrict__ partial) {
  int b = blockIdx.x >> 4, blk = blockIdx.x & 15;
  __shared__ unsigned lh[NBINS];           // 64KB
  __shared__ float rm[256], rs[256];
  for (int i = threadIdx.x; i < NBINS; i += 256) lh[i] = 0;
  __syncthreads();

  const float* row = labels + (size_t)b * NA;
  const int chunk = NA / 16;               // 9216, divisible by 256
  int base = blk * chunk;
  float m = -INFINITY, s = 0.f;
  for (int i = threadIdx.x; i < chunk; i += 256) {
    float v = row[base + i];
    atomicAdd(&lh[mkey(v) >> 18], 1u);
    if (v > m) { s = s * expf(m - v) + 1.f; m = v; }
    else       { s += expf(v - m); }
  }
  rm[threadIdx.x] = m; rs[threadIdx.x] = s;
  __syncthreads();
  for (int off = 128; off > 0; off >>= 1) {
    if (threadIdx.x < off) {
      float m1 = rm[threadIdx.x], s1 = rs[threadIdx.x];
      float m2 = rm[threadIdx.x + off], s2 = rs[threadIdx.x + off];
      float M = fmaxf(m1, m2);
      rm[threadIdx.x] = M;
      rs[threadIdx.x] = s1 * expf(m1 - M) + s2 * expf(m2 - M);
    }
    __syncthreads();
  }
  if (threadIdx.x == 0) partial[blockIdx.x] = make_float2(rm[0], rs[0]);
  for (int i = threadIdx.x; i < NBINS; i += 256) {
    unsigned c = lh[i];
    if (c) atomicAdd(&hist[b * NBINS + i], c);
  }
}

// ---------------- K2: finalize (m,S), find threshold bin ---------------------
__global__ __launch_bounds__(1024) void k_threshold(const unsigned* __restrict__ hist,
                                                    const float2* __restrict__ partial,
                                                    float4* __restrict__ meta) {
  int b = blockIdx.x;
  __shared__ float red_m, red_s;
  __shared__ unsigned cs[1024];
  if (threadIdx.x == 0) {
    float m = -INFINITY, s = 0.f;
    for (int i = 0; i < 16; ++i) {
      float2 p = partial[b * 16 + i];
      float M = fmaxf(m, p.x);
      s = s * expf(m - M) + p.y * expf(p.x - M);
      m = M;
    }
    red_m = m; red_s = s;
  }
  const unsigned* h = hist + (size_t)b * NBINS;
  int t = threadIdx.x;
  unsigned local[16], lsum = 0;
  for (int q = 0; q < 16; ++q) {            // rank r = t*16+q, bin = NBINS-1-r (scan from top)
    local[q] = h[NBINS - 1 - (t * 16 + q)];
    lsum += local[q];
  }
  cs[t] = lsum;
  __syncthreads();
  for (int off = 1; off < 1024; off <<= 1) {  // Hillis-Steele inclusive scan
    unsigned v = (t >= off) ? cs[t - off] : 0u;
    __syncthreads();
    cs[t] += v;
    __syncthreads();
  }
  unsigned incl = cs[t], excl = incl - lsum;
  if (excl < NPOST && incl >= NPOST) {
    unsigned running = excl;
    for (int q = 0; q < 16; ++q) {
      unsigned c = local[q];
      if (running < NPOST && running + c >= NPOST) {
        unsigned bin = NBINS - 1 - (t * 16 + q);
        meta[b] = make_float4(red_m, red_s, __uint_as_float(bin), 0.f);
      }
      running += c;
    }
  }
}

// ---------------- K3: compact candidates, atomic-free segmented --------------
// Each (b,blk) block owns cand[b*2048 + blk*128 .. +128): block-local LDS scan
// assigns positions; unused slots zero-filled. No global atomics anywhere.
__global__ __launch_bounds__(256) void k_compact(const float* __restrict__ labels,
                                                 const float4* __restrict__ meta,
                                                 ull* __restrict__ cand) {
  int b = blockIdx.x >> 4, blk = blockIdx.x & 15;
  unsigned tb = __float_as_uint(meta[b].z);
  const int chunk = NA / 16;               // 9216 floats = 2304 float4
  const float4* row4 = (const float4*)(labels + (size_t)b * NA + blk * chunk);
  int tid = threadIdx.x;

  float4 v[9];
#pragma unroll
  for (int it = 0; it < 9; ++it)
    v[it] = row4[it * 256 + tid];

  unsigned c = 0;
#pragma unroll
  for (int it = 0; it < 9; ++it) {
    c += ((mkey(v[it].x) >> 18) >= tb);
    c += ((mkey(v[it].y) >> 18) >= tb);
    c += ((mkey(v[it].z) >> 18) >= tb);
    c += ((mkey(v[it].w) >> 18) >= tb);
  }

  __shared__ unsigned ssum[256];
  __shared__ unsigned stotal;
  ssum[tid] = c;
  __syncthreads();
  for (int off = 1; off < 256; off <<= 1) {
    unsigned t = (tid >= off) ? ssum[tid - off] : 0u;
    __syncthreads();
    ssum[tid] += t;
    __syncthreads();
  }
  unsigned pos = ssum[tid] - c;            // exclusive prefix
  if (tid == 255) stotal = ssum[255];
  __syncthreads();

  ull* cb = cand + (size_t)b * CAND_CAP + blk * SEG;
  if (c) {
#pragma unroll
    for (int it = 0; it < 9; ++it) {
      float vals[4] = {v[it].x, v[it].y, v[it].z, v[it].w};
#pragma unroll
      for (int j = 0; j < 4; ++j) {
        unsigned kk = mkey(vals[j]);
        if ((kk >> 18) >= tb) {
          unsigned idx = (unsigned)(blk * chunk + (it * 256 + tid) * 4 + j);
          if (pos < SEG) cb[pos] = ((ull)kk << 32) | (unsigned)~idx;
          pos++;
        }
      }
    }
  }
  for (unsigned i = stotal + tid; i < SEG; i += 256) cb[i] = 0ULL;
}

// ---------------- K4: bitonic sort candidates, emit top-1000 boxes/scores ----
__global__ __launch_bounds__(1024) void k_sort_emit(const ull* __restrict__ cand,
                                                    const float4* __restrict__ meta,
                                                    const float* __restrict__ labels,
                                                    const float* __restrict__ deltas,
                                                    const float4* __restrict__ anchors,
                                                    const float* __restrict__ variances,
                                                    float4* __restrict__ sboxes,
                                                    float* __restrict__ sscores) {
  int b = blockIdx.x;
  __shared__ ull sd[CAND_CAP];
  for (int i = threadIdx.x; i < CAND_CAP; i += 1024)
    sd[i] = cand[(size_t)b * CAND_CAP + i];  // zero-padded segments

  // bitonic sort, descending (key desc, index asc via ~idx in low bits)
  for (int k = 2; k <= CAND_CAP; k <<= 1) {
    for (int j = k >> 1; j > 0; j >>= 1) {
      __syncthreads();
      for (int e = threadIdx.x; e < CAND_CAP; e += 1024) {
        int x = e ^ j;
        if (x > e) {
          ull a = sd[e], c = sd[x];
          bool up = (e & k) == 0;
          if (up ? (a < c) : (a > c)) { sd[e] = c; sd[x] = a; }
        }
      }
    }
  }
  __syncthreads();

  int r = threadIdx.x;
  if (r < NPOST) {
    ull en = sd[r];
    unsigned idx = ~(unsigned)(en & 0xFFFFFFFFu);
    float4 mt = meta[b];
    float lab = labels[(size_t)b * NA + idx];
    float score = expf(lab - mt.x) / mt.y;

    float4 an = anchors[idx];                     // [y1,x1,y2,x2]
    float aw = an.w - an.y;
    float ah = an.z - an.x;
    float acx = an.y + 0.5f * aw;
    float acy = an.x + 0.5f * ah;
    float4 dl = *(const float4*)(deltas + ((size_t)b * NA + idx) * 4);
    float4 var = *(const float4*)variances;
    float t0 = dl.x * var.x, t1 = dl.y * var.y, t2 = dl.z * var.z, t3 = dl.w * var.w;
    float bw = expf(t3) * aw;
    float bh = expf(t2) * ah;
    float bcx = t1 * aw + acx;
    float bcy = t0 * ah + acy;
    float y1 = bcy - 0.5f * bh, x1 = bcx - 0.5f * bw;
    float y2 = bh + y1, x2 = bw + x1;
    sboxes[(size_t)b * NPOST + r] = make_float4(y1, x1, y2, x2);
    sscores[(size_t)b * NPOST + r] = score;
  }
}

// ---------------- K5: pairwise IoU suppression bitmask -----------------------
__global__ __launch_bounds__(256) void k_mask(const float4* __restrict__ sboxes,
                                              ull* __restrict__ mask) {
  int b = blockIdx.x / 63, tile = blockIdx.x % 63;
  __shared__ float4 bx[NPOST];               // 16KB
  for (int j = threadIdx.x; j < NPOST; j += 256) bx[j] = sboxes[(size_t)b * NPOST + j];
  __syncthreads();
  int il = threadIdx.x >> 4, w = threadIdx.x & 15;
  int i = tile * 16 + il;
  if (i < NPOST) {
    float4 bi = bx[i];
    float ay1 = bi.x, ax1 = bi.y, ay2 = bi.z, ax2 = bi.w;
    float areai = (ay2 - ay1) * (ax2 - ax1);
    ull bits = 0;
    for (int jj = 0; jj < 64; ++jj) {
      int jb = (jj + w) & 63;                // skew to dodge LDS bank conflicts
      int j = (w << 6) + jb;
      if (j > i && j < NPOST) {
        float4 bj = bx[j];
        float areaj = (bj.z - bj.x) * (bj.w - bj.y);
        float iy1 = fmaxf(ay1, bj.x), ix1 = fmaxf(ax1, bj.y);
        float iy2 = fminf(ay2, bj.z), ix2 = fminf(ax2, bj.w);
        float inter = fmaxf(iy2 - iy1, 0.f) * fmaxf(ix2 - ix1, 0.f);
        float uni = areai + areaj - inter;
        float iou = inter / fmaxf(uni, 1e-9f);
        if (iou > 0.7f) bits |= (1ull << jb);
      }
    }
    mask[((size_t)b * NPOST + i) * 16 + w] = bits;
  }
}

// ---------------- K6: serial greedy NMS, shfl-free chain ---------------------
__global__ __launch_bounds__(256) void k_nms(const ull* __restrict__ mask,
                                             const float4* __restrict__ sboxes,
                                             const float* __restrict__ sscores,
                                             float* __restrict__ out) {
  int b = blockIdx.x;
  __shared__ ull keepw[16];
  __shared__ int pref[17];
  int tid = threadIdx.x;

  if (tid < 64) {
    int lane = tid;
    const ull* Mrow = mask + (size_t)b * NPOST * 16;
    int wsel = lane & 15;
    ull vremv = 0;
    ull buf[32];                             // 32-deep static prefetch ring
#pragma unroll
    for (int d = 0; d < 32; ++d)
      buf[d] = Mrow[(size_t)d * 16 + wsel];

#pragma unroll 1
    for (int w = 0; w < 16; ++w) {
      ull rm = readlane64(vremv, w);
#pragma unroll 1
      for (int b0 = 0; b0 < 64; b0 += 32) {
#pragma unroll
        for (int d = 0; d < 32; ++d) {
          int t = w * 64 + b0 + d;           // scan index (padded to 1024)
          ull cur = buf[d];
          int nx = t + 32;
          int rc = nx < NPOST ? nx : NPOST - 1;  // row 999's mask row is all-zero
          buf[d] = Mrow[(size_t)rc * 16 + wsel];
          int bit = b0 + d;
          if (!((rm >> bit) & 1ull)) {
            vremv |= cur;
            rm = readlane64(vremv, w);
          }
        }
      }
      if (lane == 0) keepw[w] = (w == 15) ? (~rm & ((1ull << 40) - 1)) : ~rm;
    }
    if (lane == 0) {
      int a = 0;
      for (int w = 0; w < 16; ++w) { pref[w] = a; a += __popcll(keepw[w]); }
      pref[16] = a;
    }
  }
  __syncthreads();

  int total = pref[16];
  float4* ob = (float4*)out;                 // boxes: 16*1000 float4
  float* os = out + (size_t)NB * NPOST * 4;  // scores: 16*1000 floats
  for (int r = tid; r < NPOST; r += 256) {
    if (r >= total) {
      ob[(size_t)b * NPOST + r] = make_float4(0.f, 0.f, 0.f, 0.f);
      os[(size_t)b * NPOST + r] = 0.f;
    }
  }
  for (int r = tid; r < NPOST; r += 256) {
    int w = r >> 6, bb = r & 63;
    ull kw = keepw[w];
    if ((kw >> bb) & 1ull) {
      int pos = pref[w] + __popcll(bb ? (kw & ((1ull << bb) - 1)) : 0ull);
      ob[(size_t)b * NPOST + pos] = sboxes[(size_t)b * NPOST + r];
      os[(size_t)b * NPOST + pos] = sscores[(size_t)b * NPOST + r];
    }
  }
}

extern "C" void kernel_launch(void* const* d_in, const int* in_sizes, int n_in,
                              void* d_out, int out_size, void* d_ws, size_t ws_size,
                              hipStream_t stream) {
  const float* deltas    = (const float*)d_in[0];
  const float* labels    = (const float*)d_in[1];
  const float* anchors   = (const float*)d_in[2];
  const float* variances = (const float*)d_in[3];

  char* ws = (char*)d_ws;
  ull*      cand    = (ull*)(ws + OFF_CAND);
  ull*      mask    = (ull*)(ws + OFF_MASK);
  unsigned* hist    = (unsigned*)(ws + OFF_HIST);
  float2*   partial = (float2*)(ws + OFF_PART);
  float4*   meta    = (float4*)(ws + OFF_META);
  float4*   sboxes  = (float4*)(ws + OFF_SBOX);
  float*    sscores = (float*)(ws + OFF_SSCORE);

  k_init<<<256, 256, 0, stream>>>(hist);
  k_reduce_hist<<<NB * 16, 256, 0, stream>>>(labels, hist, partial);
  k_threshold<<<NB, 1024, 0, stream>>>(hist, partial, meta);
  k_compact<<<NB * 16, 256, 0, stream>>>(labels, meta, cand);
  k_sort_emit<<<NB, 1024, 0, stream>>>(cand, meta, labels, deltas,
                                       (const float4*)anchors, variances,
                                       sboxes, sscores);
  k_mask<<<NB * 63, 256, 0, stream>>>(sboxes, mask);
  k_nms<<<NB, 256, 0, stream>>>(mask, sboxes, sscores, (float*)d_out);
}

// Round 6
// 140.841 us; speedup vs baseline: 2.1621x; 1.0352x over previous
//
#include <hip/hip_runtime.h>

typedef unsigned long long ull;

#define NA 147456
#define NB 16
#define NBINS 16384        // top-14 bits of monotonic key
#define CAND_CAP 2048
#define SEG 128            // CAND_CAP / 16 chunks
#define NPOST 1000

// ws layout (bytes)
#define OFF_CAND    0                    // 16*2048*8      = 262144
#define OFF_MASK    262144               // 16*1000*16*8   = 2048000
#define OFF_HIST    2310144              // 16*16384*4     = 1048576
#define OFF_PART    3358720              // 16*16*8        = 2048
#define OFF_META    3360768              // 16*16          = 256
#define OFF_SBOX    3361088              // 16*1000*16     = 256000
#define OFF_SSCORE  3617088              // 16*1000*4      = 64000

__device__ __forceinline__ unsigned mkey(float f) {
  unsigned u = __float_as_uint(f);
  return u ^ ((unsigned)((int)u >> 31) | 0x80000000u);  // monotonic: bigger float -> bigger key
}

__device__ __forceinline__ ull readlane64(ull v, int lane) {
  unsigned lo = (unsigned)__builtin_amdgcn_readlane((int)(unsigned)(v & 0xFFFFFFFFu), lane);
  unsigned hi = (unsigned)__builtin_amdgcn_readlane((int)(unsigned)(v >> 32), lane);
  return ((ull)hi << 32) | lo;
}

// ---------------- K0: zero hist (ws is poisoned 0xAA) ------------------------
__global__ void k_init(unsigned* hist) {
  int n = NB * NBINS;
  for (int i = blockIdx.x * blockDim.x + threadIdx.x; i < n; i += gridDim.x * blockDim.x)
    hist[i] = 0;
}

// ---------------- K1: fused online softmax-reduce + 14-bit histogram ---------
__global__ __launch_bounds__(256) void k_reduce_hist(const float* __restrict__ labels,
                                                     unsigned* __restrict__ hist,
                                                     float2* __restrict__ partial) {
  int b = blockIdx.x >> 4, blk = blockIdx.x & 15;
  __shared__ unsigned lh[NBINS];           // 64KB
  __shared__ float rm[256], rs[256];
  for (int i = threadIdx.x; i < NBINS; i += 256) lh[i] = 0;
  __syncthreads();

  const float* row = labels + (size_t)b * NA;
  const int chunk = NA / 16;               // 9216, divisible by 256
  int base = blk * chunk;
  float m = -INFINITY, s = 0.f;
  for (int i = threadIdx.x; i < chunk; i += 256) {
    float v = row[base + i];
    atomicAdd(&lh[mkey(v) >> 18], 1u);
    if (v > m) { s = s * expf(m - v) + 1.f; m = v; }
    else       { s += expf(v - m); }
  }
  rm[threadIdx.x] = m; rs[threadIdx.x] = s;
  __syncthreads();
  for (int off = 128; off > 0; off >>= 1) {
    if (threadIdx.x < off) {
      float m1 = rm[threadIdx.x], s1 = rs[threadIdx.x];
      float m2 = rm[threadIdx.x + off], s2 = rs[threadIdx.x + off];
      float M = fmaxf(m1, m2);
      rm[threadIdx.x] = M;
      rs[threadIdx.x] = s1 * expf(m1 - M) + s2 * expf(m2 - M);
    }
    __syncthreads();
  }
  if (threadIdx.x == 0) partial[blockIdx.x] = make_float2(rm[0], rs[0]);
  for (int i = threadIdx.x; i < NBINS; i += 256) {
    unsigned c = lh[i];
    if (c) atomicAdd(&hist[b * NBINS + i], c);
  }
}

// ---------------- K2: finalize (m,S), find threshold bin ---------------------
__global__ __launch_bounds__(1024) void k_threshold(const unsigned* __restrict__ hist,
                                                    const float2* __restrict__ partial,
                                                    float4* __restrict__ meta) {
  int b = blockIdx.x;
  __shared__ float red_m, red_s;
  __shared__ unsigned cs[1024];
  if (threadIdx.x == 0) {
    float m = -INFINITY, s = 0.f;
    for (int i = 0; i < 16; ++i) {
      float2 p = partial[b * 16 + i];
      float M = fmaxf(m, p.x);
      s = s * expf(m - M) + p.y * expf(p.x - M);
      m = M;
    }
    red_m = m; red_s = s;
  }
  const unsigned* h = hist + (size_t)b * NBINS;
  int t = threadIdx.x;
  unsigned local[16], lsum = 0;
  for (int q = 0; q < 16; ++q) {            // rank r = t*16+q, bin = NBINS-1-r (scan from top)
    local[q] = h[NBINS - 1 - (t * 16 + q)];
    lsum += local[q];
  }
  cs[t] = lsum;
  __syncthreads();
  for (int off = 1; off < 1024; off <<= 1) {  // Hillis-Steele inclusive scan
    unsigned v = (t >= off) ? cs[t - off] : 0u;
    __syncthreads();
    cs[t] += v;
    __syncthreads();
  }
  unsigned incl = cs[t], excl = incl - lsum;
  if (excl < NPOST && incl >= NPOST) {
    unsigned running = excl;
    for (int q = 0; q < 16; ++q) {
      unsigned c = local[q];
      if (running < NPOST && running + c >= NPOST) {
        unsigned bin = NBINS - 1 - (t * 16 + q);
        meta[b] = make_float4(red_m, red_s, __uint_as_float(bin), 0.f);
      }
      running += c;
    }
  }
}

// ---------------- K3: compact candidates, atomic-free segmented --------------
__global__ __launch_bounds__(256) void k_compact(const float* __restrict__ labels,
                                                 const float4* __restrict__ meta,
                                                 ull* __restrict__ cand) {
  int b = blockIdx.x >> 4, blk = blockIdx.x & 15;
  unsigned tb = __float_as_uint(meta[b].z);
  const int chunk = NA / 16;               // 9216 floats = 2304 float4
  const float4* row4 = (const float4*)(labels + (size_t)b * NA + blk * chunk);
  int tid = threadIdx.x;

  float4 v[9];
#pragma unroll
  for (int it = 0; it < 9; ++it)
    v[it] = row4[it * 256 + tid];

  unsigned c = 0;
#pragma unroll
  for (int it = 0; it < 9; ++it) {
    c += ((mkey(v[it].x) >> 18) >= tb);
    c += ((mkey(v[it].y) >> 18) >= tb);
    c += ((mkey(v[it].z) >> 18) >= tb);
    c += ((mkey(v[it].w) >> 18) >= tb);
  }

  __shared__ unsigned ssum[256];
  __shared__ unsigned stotal;
  ssum[tid] = c;
  __syncthreads();
  for (int off = 1; off < 256; off <<= 1) {
    unsigned t = (tid >= off) ? ssum[tid - off] : 0u;
    __syncthreads();
    ssum[tid] += t;
    __syncthreads();
  }
  unsigned pos = ssum[tid] - c;            // exclusive prefix
  if (tid == 255) stotal = ssum[255];
  __syncthreads();

  ull* cb = cand + (size_t)b * CAND_CAP + blk * SEG;
  if (c) {
#pragma unroll
    for (int it = 0; it < 9; ++it) {
      float vals[4] = {v[it].x, v[it].y, v[it].z, v[it].w};
#pragma unroll
      for (int j = 0; j < 4; ++j) {
        unsigned kk = mkey(vals[j]);
        if ((kk >> 18) >= tb) {
          unsigned idx = (unsigned)(blk * chunk + (it * 256 + tid) * 4 + j);
          if (pos < SEG) cb[pos] = ((ull)kk << 32) | (unsigned)~idx;
          pos++;
        }
      }
    }
  }
  for (unsigned i = stotal + tid; i < SEG; i += 256) cb[i] = 0ULL;
}

// ---------------- K4: bitonic sort candidates, emit top-1000 boxes/scores ----
__global__ __launch_bounds__(1024) void k_sort_emit(const ull* __restrict__ cand,
                                                    const float4* __restrict__ meta,
                                                    const float* __restrict__ labels,
                                                    const float* __restrict__ deltas,
                                                    const float4* __restrict__ anchors,
                                                    const float* __restrict__ variances,
                                                    float4* __restrict__ sboxes,
                                                    float* __restrict__ sscores) {
  int b = blockIdx.x;
  __shared__ ull sd[CAND_CAP];
  for (int i = threadIdx.x; i < CAND_CAP; i += 1024)
    sd[i] = cand[(size_t)b * CAND_CAP + i];  // zero-padded segments

  // bitonic sort, descending (key desc, index asc via ~idx in low bits)
  for (int k = 2; k <= CAND_CAP; k <<= 1) {
    for (int j = k >> 1; j > 0; j >>= 1) {
      __syncthreads();
      for (int e = threadIdx.x; e < CAND_CAP; e += 1024) {
        int x = e ^ j;
        if (x > e) {
          ull a = sd[e], c = sd[x];
          bool up = (e & k) == 0;
          if (up ? (a < c) : (a > c)) { sd[e] = c; sd[x] = a; }
        }
      }
    }
  }
  __syncthreads();

  int r = threadIdx.x;
  if (r < NPOST) {
    ull en = sd[r];
    unsigned idx = ~(unsigned)(en & 0xFFFFFFFFu);
    float4 mt = meta[b];
    float lab = labels[(size_t)b * NA + idx];
    float score = expf(lab - mt.x) / mt.y;

    float4 an = anchors[idx];                     // [y1,x1,y2,x2]
    float aw = an.w - an.y;
    float ah = an.z - an.x;
    float acx = an.y + 0.5f * aw;
    float acy = an.x + 0.5f * ah;
    float4 dl = *(const float4*)(deltas + ((size_t)b * NA + idx) * 4);
    float4 var = *(const float4*)variances;
    float t0 = dl.x * var.x, t1 = dl.y * var.y, t2 = dl.z * var.z, t3 = dl.w * var.w;
    float bw = expf(t3) * aw;
    float bh = expf(t2) * ah;
    float bcx = t1 * aw + acx;
    float bcy = t0 * ah + acy;
    float y1 = bcy - 0.5f * bh, x1 = bcx - 0.5f * bw;
    float y2 = bh + y1, x2 = bw + x1;
    sboxes[(size_t)b * NPOST + r] = make_float4(y1, x1, y2, x2);
    sscores[(size_t)b * NPOST + r] = score;
  }
}

// ---------------- K5: pairwise IoU suppression bitmask -----------------------
__global__ __launch_bounds__(256) void k_mask(const float4* __restrict__ sboxes,
                                              ull* __restrict__ mask) {
  int b = blockIdx.x / 63, tile = blockIdx.x % 63;
  __shared__ float4 bx[NPOST];               // 16KB
  for (int j = threadIdx.x; j < NPOST; j += 256) bx[j] = sboxes[(size_t)b * NPOST + j];
  __syncthreads();
  int il = threadIdx.x >> 4, w = threadIdx.x & 15;
  int i = tile * 16 + il;
  if (i < NPOST) {
    float4 bi = bx[i];
    float ay1 = bi.x, ax1 = bi.y, ay2 = bi.z, ax2 = bi.w;
    float areai = (ay2 - ay1) * (ax2 - ax1);
    ull bits = 0;
    for (int jj = 0; jj < 64; ++jj) {
      int jb = (jj + w) & 63;                // skew to dodge LDS bank conflicts
      int j = (w << 6) + jb;
      if (j > i && j < NPOST) {
        float4 bj = bx[j];
        float areaj = (bj.z - bj.x) * (bj.w - bj.y);
        float iy1 = fmaxf(ay1, bj.x), ix1 = fmaxf(ax1, bj.y);
        float iy2 = fminf(ay2, bj.z), ix2 = fminf(ax2, bj.w);
        float inter = fmaxf(iy2 - iy1, 0.f) * fmaxf(ix2 - ix1, 0.f);
        float uni = areai + areaj - inter;
        float iou = inter / fmaxf(uni, 1e-9f);
        if (iou > 0.7f) bits |= (1ull << jb);
      }
    }
    mask[((size_t)b * NPOST + i) * 16 + w] = bits;
  }
}

// ---------------- K6: greedy NMS, ballot-marshaled scalar inner loop ---------
// Phase w (64 bits): keep[c] = !rm0[c] && (col_c & kmask)==0, using the
// upper-triangular structure of the mask (row i only suppresses j>i).
// col_c marshaled wave->SGPR via __ballot; cross-word suppression accumulated
// vector-side (lane l owns word l&15); one readlane64 per PHASE.
__global__ __launch_bounds__(256) void k_nms(const ull* __restrict__ mask,
                                             const float4* __restrict__ sboxes,
                                             const float* __restrict__ sscores,
                                             float* __restrict__ out) {
  int b = blockIdx.x;
  __shared__ ull keepw[16];
  __shared__ int pref[17];
  int tid = threadIdx.x;

  if (tid < 64) {
    int lane = tid;
    const ull* Mrow = mask + (size_t)b * NPOST * 16;
    int wsel = lane & 15;
    ull vremv = 0;

    // register ring: rows of current phase, word wsel (refilled one phase ahead)
    ull ring[64];
#pragma unroll
    for (int d = 0; d < 64; ++d)
      ring[d] = Mrow[(size_t)d * 16 + wsel];

    // q for phase 0: lane d = row d's word 0
    ull qcur = Mrow[(size_t)lane * 16 + 0];

#pragma unroll 1
    for (int w = 0; w < 16; ++w) {
      // issue next phase's q early (latency hidden under this phase)
      int nw = (w + 1) & 15;
      int nrow = (w + 1) * 64 + lane; nrow = nrow < NPOST ? nrow : NPOST - 1;
      ull qnext = Mrow[(size_t)nrow * 16 + nw];

      ull rm0 = readlane64(vremv, w);        // suppression word w from prior phases
      ull kmask = 0;
#pragma unroll
      for (int cb = 0; cb < 4; ++cb) {
        ull cols[16];
#pragma unroll
        for (int c = 0; c < 16; ++c) {
          int cc = cb * 16 + c;
          cols[c] = __ballot(((qcur >> cc) & 1ull) != 0ull);
        }
#pragma unroll
        for (int c = 0; c < 16; ++c) {
          int cc = cb * 16 + c;
          bool k = (((rm0 >> cc) & 1ull) == 0ull) && ((cols[c] & kmask) == 0ull);
          kmask |= k ? (1ull << cc) : 0ull;
        }
      }
      if (w == 15) kmask &= (1ull << 40) - 1;   // rows 1000..1023 invalid
      if (lane == 0) keepw[w] = kmask;

      if (w < 15) {
        // accumulate kept rows into vremv; refill ring with next phase's rows
#pragma unroll
        for (int d = 0; d < 64; ++d) {
          ull r = ring[d];
          int rr = (w + 1) * 64 + d; rr = rr < NPOST ? rr : NPOST - 1;
          ring[d] = Mrow[(size_t)rr * 16 + wsel];
          vremv |= ((kmask >> d) & 1ull) ? r : 0ull;
        }
      }
      qcur = qnext;
    }

    if (lane == 0) {
      int a = 0;
      for (int w = 0; w < 16; ++w) { pref[w] = a; a += __popcll(keepw[w]); }
      pref[16] = a;
    }
  }
  __syncthreads();

  int total = pref[16];
  float4* ob = (float4*)out;                 // boxes: 16*1000 float4
  float* os = out + (size_t)NB * NPOST * 4;  // scores: 16*1000 floats
  for (int r = tid; r < NPOST; r += 256) {
    if (r >= total) {
      ob[(size_t)b * NPOST + r] = make_float4(0.f, 0.f, 0.f, 0.f);
      os[(size_t)b * NPOST + r] = 0.f;
    }
  }
  for (int r = tid; r < NPOST; r += 256) {
    int w = r >> 6, bb = r & 63;
    ull kw = keepw[w];
    if ((kw >> bb) & 1ull) {
      int pos = pref[w] + __popcll(bb ? (kw & ((1ull << bb) - 1)) : 0ull);
      ob[(size_t)b * NPOST + pos] = sboxes[(size_t)b * NPOST + r];
      os[(size_t)b * NPOST + pos] = sscores[(size_t)b * NPOST + r];
    }
  }
}

extern "C" void kernel_launch(void* const* d_in, const int* in_sizes, int n_in,
                              void* d_out, int out_size, void* d_ws, size_t ws_size,
                              hipStream_t stream) {
  const float* deltas    = (const float*)d_in[0];
  const float* labels    = (const float*)d_in[1];
  const float* anchors   = (const float*)d_in[2];
  const float* variances = (const float*)d_in[3];

  char* ws = (char*)d_ws;
  ull*      cand    = (ull*)(ws + OFF_CAND);
  ull*      mask    = (ull*)(ws + OFF_MASK);
  unsigned* hist    = (unsigned*)(ws + OFF_HIST);
  float2*   partial = (float2*)(ws + OFF_PART);
  float4*   meta    = (float4*)(ws + OFF_META);
  float4*   sboxes  = (float4*)(ws + OFF_SBOX);
  float*    sscores = (float*)(ws + OFF_SSCORE);

  k_init<<<256, 256, 0, stream>>>(hist);
  k_reduce_hist<<<NB * 16, 256, 0, stream>>>(labels, hist, partial);
  k_threshold<<<NB, 1024, 0, stream>>>(hist, partial, meta);
  k_compact<<<NB * 16, 256, 0, stream>>>(labels, meta, cand);
  k_sort_emit<<<NB, 1024, 0, stream>>>(cand, meta, labels, deltas,
                                       (const float4*)anchors, variances,
                                       sboxes, sscores);
  k_mask<<<NB * 63, 256, 0, stream>>>(sboxes, mask);
  k_nms<<<NB, 256, 0, stream>>>(mask, sboxes, sscores, (float*)d_out);
}

// Round 7
// 132.015 us; speedup vs baseline: 2.3066x; 1.0669x over previous
//
#include <hip/hip_runtime.h>

typedef unsigned long long ull;

#define NA 147456
#define NB 16
#define NBINS 16384        // top-14 bits of monotonic key
#define CAND_CAP 2048
#define SEG 128            // CAND_CAP / 16 chunks
#define NPOST 1000

// ws layout (bytes)
#define OFF_CAND    0                    // 16*2048*8      = 262144
#define OFF_MASK    262144               // 16*1000*16*8   = 2048000 (maskT now)
#define OFF_HIST    2310144              // 16*16384*4     = 1048576
#define OFF_PART    3358720              // 16*16*8        = 2048
#define OFF_META    3360768              // 16*16          = 256
#define OFF_SBOX    3361088              // 16*1000*16     = 256000
#define OFF_SSCORE  3617088              // 16*1000*4      = 64000

__device__ __forceinline__ unsigned mkey(float f) {
  unsigned u = __float_as_uint(f);
  return u ^ ((unsigned)((int)u >> 31) | 0x80000000u);  // monotonic: bigger float -> bigger key
}

__device__ __forceinline__ ull readlane64(ull v, int lane) {
  unsigned lo = (unsigned)__builtin_amdgcn_readlane((int)(unsigned)(v & 0xFFFFFFFFu), lane);
  unsigned hi = (unsigned)__builtin_amdgcn_readlane((int)(unsigned)(v >> 32), lane);
  return ((ull)hi << 32) | lo;
}

// ---------------- K0: zero hist (ws is poisoned 0xAA) ------------------------
__global__ void k_init(unsigned* hist) {
  int n = NB * NBINS;
  for (int i = blockIdx.x * blockDim.x + threadIdx.x; i < n; i += gridDim.x * blockDim.x)
    hist[i] = 0;
}

// ---------------- K1: fused online softmax-reduce + 14-bit histogram ---------
__global__ __launch_bounds__(256) void k_reduce_hist(const float* __restrict__ labels,
                                                     unsigned* __restrict__ hist,
                                                     float2* __restrict__ partial) {
  int b = blockIdx.x >> 4, blk = blockIdx.x & 15;
  __shared__ unsigned lh[NBINS];           // 64KB
  __shared__ float rm[256], rs[256];
  for (int i = threadIdx.x; i < NBINS; i += 256) lh[i] = 0;
  __syncthreads();

  const float* row = labels + (size_t)b * NA;
  const int chunk = NA / 16;               // 9216, divisible by 256
  int base = blk * chunk;
  float m = -INFINITY, s = 0.f;
  for (int i = threadIdx.x; i < chunk; i += 256) {
    float v = row[base + i];
    atomicAdd(&lh[mkey(v) >> 18], 1u);
    if (v > m) { s = s * expf(m - v) + 1.f; m = v; }
    else       { s += expf(v - m); }
  }
  rm[threadIdx.x] = m; rs[threadIdx.x] = s;
  __syncthreads();
  for (int off = 128; off > 0; off >>= 1) {
    if (threadIdx.x < off) {
      float m1 = rm[threadIdx.x], s1 = rs[threadIdx.x];
      float m2 = rm[threadIdx.x + off], s2 = rs[threadIdx.x + off];
      float M = fmaxf(m1, m2);
      rm[threadIdx.x] = M;
      rs[threadIdx.x] = s1 * expf(m1 - M) + s2 * expf(m2 - M);
    }
    __syncthreads();
  }
  if (threadIdx.x == 0) partial[blockIdx.x] = make_float2(rm[0], rs[0]);
  for (int i = threadIdx.x; i < NBINS; i += 256) {
    unsigned c = lh[i];
    if (c) atomicAdd(&hist[b * NBINS + i], c);
  }
}

// ---------------- K2: finalize (m,S), find threshold bin ---------------------
__global__ __launch_bounds__(1024) void k_threshold(const unsigned* __restrict__ hist,
                                                    const float2* __restrict__ partial,
                                                    float4* __restrict__ meta) {
  int b = blockIdx.x;
  __shared__ float red_m, red_s;
  __shared__ unsigned cs[1024];
  if (threadIdx.x == 0) {
    float m = -INFINITY, s = 0.f;
    for (int i = 0; i < 16; ++i) {
      float2 p = partial[b * 16 + i];
      float M = fmaxf(m, p.x);
      s = s * expf(m - M) + p.y * expf(p.x - M);
      m = M;
    }
    red_m = m; red_s = s;
  }
  const unsigned* h = hist + (size_t)b * NBINS;
  int t = threadIdx.x;
  unsigned local[16], lsum = 0;
  for (int q = 0; q < 16; ++q) {            // rank r = t*16+q, bin = NBINS-1-r (scan from top)
    local[q] = h[NBINS - 1 - (t * 16 + q)];
    lsum += local[q];
  }
  cs[t] = lsum;
  __syncthreads();
  for (int off = 1; off < 1024; off <<= 1) {  // Hillis-Steele inclusive scan
    unsigned v = (t >= off) ? cs[t - off] : 0u;
    __syncthreads();
    cs[t] += v;
    __syncthreads();
  }
  unsigned incl = cs[t], excl = incl - lsum;
  if (excl < NPOST && incl >= NPOST) {
    unsigned running = excl;
    for (int q = 0; q < 16; ++q) {
      unsigned c = local[q];
      if (running < NPOST && running + c >= NPOST) {
        unsigned bin = NBINS - 1 - (t * 16 + q);
        meta[b] = make_float4(red_m, red_s, __uint_as_float(bin), 0.f);
      }
      running += c;
    }
  }
}

// ---------------- K3: compact candidates, atomic-free segmented --------------
__global__ __launch_bounds__(256) void k_compact(const float* __restrict__ labels,
                                                 const float4* __restrict__ meta,
                                                 ull* __restrict__ cand) {
  int b = blockIdx.x >> 4, blk = blockIdx.x & 15;
  unsigned tb = __float_as_uint(meta[b].z);
  const int chunk = NA / 16;               // 9216 floats = 2304 float4
  const float4* row4 = (const float4*)(labels + (size_t)b * NA + blk * chunk);
  int tid = threadIdx.x;

  float4 v[9];
#pragma unroll
  for (int it = 0; it < 9; ++it)
    v[it] = row4[it * 256 + tid];

  unsigned c = 0;
#pragma unroll
  for (int it = 0; it < 9; ++it) {
    c += ((mkey(v[it].x) >> 18) >= tb);
    c += ((mkey(v[it].y) >> 18) >= tb);
    c += ((mkey(v[it].z) >> 18) >= tb);
    c += ((mkey(v[it].w) >> 18) >= tb);
  }

  __shared__ unsigned ssum[256];
  __shared__ unsigned stotal;
  ssum[tid] = c;
  __syncthreads();
  for (int off = 1; off < 256; off <<= 1) {
    unsigned t = (tid >= off) ? ssum[tid - off] : 0u;
    __syncthreads();
    ssum[tid] += t;
    __syncthreads();
  }
  unsigned pos = ssum[tid] - c;            // exclusive prefix
  if (tid == 255) stotal = ssum[255];
  __syncthreads();

  ull* cb = cand + (size_t)b * CAND_CAP + blk * SEG;
  if (c) {
#pragma unroll
    for (int it = 0; it < 9; ++it) {
      float vals[4] = {v[it].x, v[it].y, v[it].z, v[it].w};
#pragma unroll
      for (int j = 0; j < 4; ++j) {
        unsigned kk = mkey(vals[j]);
        if ((kk >> 18) >= tb) {
          unsigned idx = (unsigned)(blk * chunk + (it * 256 + tid) * 4 + j);
          if (pos < SEG) cb[pos] = ((ull)kk << 32) | (unsigned)~idx;
          pos++;
        }
      }
    }
  }
  for (unsigned i = stotal + tid; i < SEG; i += 256) cb[i] = 0ULL;
}

// ---------------- K4: bitonic sort candidates, emit top-1000 boxes/scores ----
__global__ __launch_bounds__(1024) void k_sort_emit(const ull* __restrict__ cand,
                                                    const float4* __restrict__ meta,
                                                    const float* __restrict__ labels,
                                                    const float* __restrict__ deltas,
                                                    const float4* __restrict__ anchors,
                                                    const float* __restrict__ variances,
                                                    float4* __restrict__ sboxes,
                                                    float* __restrict__ sscores) {
  int b = blockIdx.x;
  __shared__ ull sd[CAND_CAP];
  for (int i = threadIdx.x; i < CAND_CAP; i += 1024)
    sd[i] = cand[(size_t)b * CAND_CAP + i];  // zero-padded segments

  // bitonic sort, descending (key desc, index asc via ~idx in low bits)
  for (int k = 2; k <= CAND_CAP; k <<= 1) {
    for (int j = k >> 1; j > 0; j >>= 1) {
      __syncthreads();
      for (int e = threadIdx.x; e < CAND_CAP; e += 1024) {
        int x = e ^ j;
        if (x > e) {
          ull a = sd[e], c = sd[x];
          bool up = (e & k) == 0;
          if (up ? (a < c) : (a > c)) { sd[e] = c; sd[x] = a; }
        }
      }
    }
  }
  __syncthreads();

  int r = threadIdx.x;
  if (r < NPOST) {
    ull en = sd[r];
    unsigned idx = ~(unsigned)(en & 0xFFFFFFFFu);
    float4 mt = meta[b];
    float lab = labels[(size_t)b * NA + idx];
    float score = expf(lab - mt.x) / mt.y;

    float4 an = anchors[idx];                     // [y1,x1,y2,x2]
    float aw = an.w - an.y;
    float ah = an.z - an.x;
    float acx = an.y + 0.5f * aw;
    float acy = an.x + 0.5f * ah;
    float4 dl = *(const float4*)(deltas + ((size_t)b * NA + idx) * 4);
    float4 var = *(const float4*)variances;
    float t0 = dl.x * var.x, t1 = dl.y * var.y, t2 = dl.z * var.z, t3 = dl.w * var.w;
    float bw = expf(t3) * aw;
    float bh = expf(t2) * ah;
    float bcx = t1 * aw + acx;
    float bcy = t0 * ah + acy;
    float y1 = bcy - 0.5f * bh, x1 = bcx - 0.5f * bw;
    float y2 = bh + y1, x2 = bw + x1;
    sboxes[(size_t)b * NPOST + r] = make_float4(y1, x1, y2, x2);
    sscores[(size_t)b * NPOST + r] = score;
  }
}

// ---------------- K5: pairwise IoU, TRANSPOSED (lower-tri) bitmask -----------
// maskT[c][w] bit d = IoU(row w*64+d, col c) > thr  &&  (w*64+d) < c
__global__ __launch_bounds__(256) void k_mask(const float4* __restrict__ sboxes,
                                              ull* __restrict__ maskT) {
  int b = blockIdx.x / 63, tile = blockIdx.x % 63;
  __shared__ float4 bx[NPOST];               // 16KB
  for (int j = threadIdx.x; j < NPOST; j += 256) bx[j] = sboxes[(size_t)b * NPOST + j];
  __syncthreads();
  int il = threadIdx.x >> 4, w = threadIdx.x & 15;
  int i = tile * 16 + il;
  if (i < NPOST) {
    float4 bi = bx[i];
    float ay1 = bi.x, ax1 = bi.y, ay2 = bi.z, ax2 = bi.w;
    float areai = (ay2 - ay1) * (ax2 - ax1);
    ull bits = 0;
    for (int jj = 0; jj < 64; ++jj) {
      int jb = (jj + w) & 63;                // skew to dodge LDS bank conflicts
      int j = (w << 6) + jb;
      if (j < i) {                           // lower-tri: rows j that suppress col i
        float4 bj = bx[j];
        float areaj = (bj.z - bj.x) * (bj.w - bj.y);
        float iy1 = fmaxf(ay1, bj.x), ix1 = fmaxf(ax1, bj.y);
        float iy2 = fminf(ay2, bj.z), ix2 = fminf(ax2, bj.w);
        float inter = fmaxf(iy2 - iy1, 0.f) * fmaxf(ix2 - ix1, 0.f);
        float uni = areai + areaj - inter;
        float iou = inter / fmaxf(uni, 1e-9f);
        if (iou > 0.7f) bits |= (1ull << jb);
      }
    }
    maskT[((size_t)b * NPOST + i) * 16 + w] = bits;
  }
}

// ---------------- K6: greedy NMS on transposed mask --------------------------
// Lane c owns column (w*64+c): cur[16] = its 16 colT words (128B contiguous).
// rm0 (cross-word suppression) recomputed per phase: ballot(OR_k cur[k]&keep[k]);
// no running vector state, no register ring, no spill. In-word chain: diagonal
// word is lane-local; marshal 16 cols at a time via v_readlane, chain in SALU.
__global__ __launch_bounds__(256) void k_nms(const ull* __restrict__ maskT,
                                             const float4* __restrict__ sboxes,
                                             const float* __restrict__ sscores,
                                             float* __restrict__ out) {
  int b = blockIdx.x;
  __shared__ ull keep_lds[16];
  __shared__ int pref[17];
  int tid = threadIdx.x;

  if (tid < 64) {
    int lane = tid;
    const ull* MT = maskT + (size_t)b * NPOST * 16;
    if (lane < 16) keep_lds[lane] = 0ULL;

    ull cur[16];
    int r0 = lane;                           // phase-0 rows all < 1000
#pragma unroll
    for (int k = 0; k < 16; ++k) cur[k] = MT[(size_t)r0 * 16 + k];
    ull qT = cur[0];

#pragma unroll 1
    for (int w = 0; w < 16; ++w) {
      // prefetch next phase's column words (clamped row; garbage is masked)
      ull nxt[16]; ull qTn;
      int nr = (w + 1) * 64 + lane; if (nr > NPOST - 1) nr = NPOST - 1;
      int nw = w + 1 < 15 ? w + 1 : 15;
#pragma unroll
      for (int k = 0; k < 16; ++k) nxt[k] = MT[(size_t)nr * 16 + k];
      qTn = MT[(size_t)nr * 16 + nw];

      // cross-word suppression for this phase's 64 columns
      ull acc = 0;
#pragma unroll
      for (int k = 0; k < 16; ++k) acc |= cur[k] & keep_lds[k];
      ull rm0 = __ballot(acc != 0ull);

      // in-word serial chain (SALU), 16 columns per marshal batch
      ull kmask = 0;
#pragma unroll 1
      for (int cb = 0; cb < 4; ++cb) {
        ull cols[16];
#pragma unroll
        for (int c = 0; c < 16; ++c) cols[c] = readlane64(qT, cb * 16 + c);
#pragma unroll
        for (int c = 0; c < 16; ++c) {
          int cc = cb * 16 + c;
          bool kp = (((rm0 >> cc) & 1ull) == 0ull) && ((cols[c] & kmask) == 0ull);
          kmask |= kp ? (1ull << cc) : 0ull;
        }
      }
      if (w == 15) kmask &= (1ull << 40) - 1;   // boxes 1000..1023 invalid
      if (lane == 0) keep_lds[w] = kmask;

#pragma unroll
      for (int k = 0; k < 16; ++k) cur[k] = nxt[k];
      qT = qTn;
    }

    if (lane == 0) {
      int a = 0;
      for (int w = 0; w < 16; ++w) { pref[w] = a; a += __popcll(keep_lds[w]); }
      pref[16] = a;
    }
  }
  __syncthreads();

  int total = pref[16];
  float4* ob = (float4*)out;                 // boxes: 16*1000 float4
  float* os = out + (size_t)NB * NPOST * 4;  // scores: 16*1000 floats
  for (int r = tid; r < NPOST; r += 256) {
    if (r >= total) {
      ob[(size_t)b * NPOST + r] = make_float4(0.f, 0.f, 0.f, 0.f);
      os[(size_t)b * NPOST + r] = 0.f;
    }
  }
  for (int r = tid; r < NPOST; r += 256) {
    int w = r >> 6, bb = r & 63;
    ull kw = keep_lds[w];
    if ((kw >> bb) & 1ull) {
      int pos = pref[w] + __popcll(bb ? (kw & ((1ull << bb) - 1)) : 0ull);
      ob[(size_t)b * NPOST + pos] = sboxes[(size_t)b * NPOST + r];
      os[(size_t)b * NPOST + pos] = sscores[(size_t)b * NPOST + r];
    }
  }
}

extern "C" void kernel_launch(void* const* d_in, const int* in_sizes, int n_in,
                              void* d_out, int out_size, void* d_ws, size_t ws_size,
                              hipStream_t stream) {
  const float* deltas    = (const float*)d_in[0];
  const float* labels    = (const float*)d_in[1];
  const float* anchors   = (const float*)d_in[2];
  const float* variances = (const float*)d_in[3];

  char* ws = (char*)d_ws;
  ull*      cand    = (ull*)(ws + OFF_CAND);
  ull*      maskT   = (ull*)(ws + OFF_MASK);
  unsigned* hist    = (unsigned*)(ws + OFF_HIST);
  float2*   partial = (float2*)(ws + OFF_PART);
  float4*   meta    = (float4*)(ws + OFF_META);
  float4*   sboxes  = (float4*)(ws + OFF_SBOX);
  float*    sscores = (float*)(ws + OFF_SSCORE);

  k_init<<<256, 256, 0, stream>>>(hist);
  k_reduce_hist<<<NB * 16, 256, 0, stream>>>(labels, hist, partial);
  k_threshold<<<NB, 1024, 0, stream>>>(hist, partial, meta);
  k_compact<<<NB * 16, 256, 0, stream>>>(labels, meta, cand);
  k_sort_emit<<<NB, 1024, 0, stream>>>(cand, meta, labels, deltas,
                                       (const float4*)anchors, variances,
                                       sboxes, sscores);
  k_mask<<<NB * 63, 256, 0, stream>>>(sboxes, maskT);
  k_nms<<<NB, 256, 0, stream>>>(maskT, sboxes, sscores, (float*)d_out);
}

// Round 8
// 120.683 us; speedup vs baseline: 2.5232x; 1.0939x over previous
//
#include <hip/hip_runtime.h>

typedef unsigned long long ull;

#define NA 147456
#define NB 16
#define NBINS 16384        // top-14 bits of monotonic key
#define CAND_CAP 2048
#define SEG 128            // CAND_CAP / 16 chunks
#define NPOST 1000

// ws layout (bytes)
#define OFF_CAND    0                    // 16*2048*8      = 262144
#define OFF_MASK    262144               // 16*1000*16*8   = 2048000 (maskT)
#define OFF_HIST    2310144              // 16*16384*4     = 1048576
#define OFF_PART    3358720              // 16*16*8        = 2048
#define OFF_META    3360768              // 16*16          = 256
#define OFF_SBOX    3361088              // 16*1000*16     = 256000
#define OFF_SSCORE  3617088              // 16*1000*4      = 64000

__device__ __forceinline__ unsigned mkey(float f) {
  unsigned u = __float_as_uint(f);
  return u ^ ((unsigned)((int)u >> 31) | 0x80000000u);  // monotonic: bigger float -> bigger key
}

__device__ __forceinline__ ull readlane64(ull v, int lane) {
  unsigned lo = (unsigned)__builtin_amdgcn_readlane((int)(unsigned)(v & 0xFFFFFFFFu), lane);
  unsigned hi = (unsigned)__builtin_amdgcn_readlane((int)(unsigned)(v >> 32), lane);
  return ((ull)hi << 32) | lo;
}

// ---------------- K0: zero hist (ws is poisoned 0xAA) ------------------------
__global__ void k_init(unsigned* hist) {
  int n = NB * NBINS;
  for (int i = blockIdx.x * blockDim.x + threadIdx.x; i < n; i += gridDim.x * blockDim.x)
    hist[i] = 0;
}

// ---------------- K1: fused online softmax-reduce + 14-bit histogram ---------
__global__ __launch_bounds__(256) void k_reduce_hist(const float* __restrict__ labels,
                                                     unsigned* __restrict__ hist,
                                                     float2* __restrict__ partial) {
  int b = blockIdx.x >> 4, blk = blockIdx.x & 15;
  __shared__ unsigned lh[NBINS];           // 64KB
  __shared__ float rm[256], rs[256];
  for (int i = threadIdx.x; i < NBINS; i += 256) lh[i] = 0;
  __syncthreads();

  const float* row = labels + (size_t)b * NA;
  const int chunk = NA / 16;               // 9216, divisible by 256
  int base = blk * chunk;
  float m = -INFINITY, s = 0.f;
  for (int i = threadIdx.x; i < chunk; i += 256) {
    float v = row[base + i];
    atomicAdd(&lh[mkey(v) >> 18], 1u);
    if (v > m) { s = s * expf(m - v) + 1.f; m = v; }
    else       { s += expf(v - m); }
  }
  rm[threadIdx.x] = m; rs[threadIdx.x] = s;
  __syncthreads();
  for (int off = 128; off > 0; off >>= 1) {
    if (threadIdx.x < off) {
      float m1 = rm[threadIdx.x], s1 = rs[threadIdx.x];
      float m2 = rm[threadIdx.x + off], s2 = rs[threadIdx.x + off];
      float M = fmaxf(m1, m2);
      rm[threadIdx.x] = M;
      rs[threadIdx.x] = s1 * expf(m1 - M) + s2 * expf(m2 - M);
    }
    __syncthreads();
  }
  if (threadIdx.x == 0) partial[blockIdx.x] = make_float2(rm[0], rs[0]);
  for (int i = threadIdx.x; i < NBINS; i += 256) {
    unsigned c = lh[i];
    if (c) atomicAdd(&hist[b * NBINS + i], c);
  }
}

// ---------------- K2: finalize (m,S), find threshold bin ---------------------
__global__ __launch_bounds__(1024) void k_threshold(const unsigned* __restrict__ hist,
                                                    const float2* __restrict__ partial,
                                                    float4* __restrict__ meta) {
  int b = blockIdx.x;
  __shared__ float red_m, red_s;
  __shared__ unsigned cs[1024];
  if (threadIdx.x == 0) {
    float m = -INFINITY, s = 0.f;
    for (int i = 0; i < 16; ++i) {
      float2 p = partial[b * 16 + i];
      float M = fmaxf(m, p.x);
      s = s * expf(m - M) + p.y * expf(p.x - M);
      m = M;
    }
    red_m = m; red_s = s;
  }
  const unsigned* h = hist + (size_t)b * NBINS;
  int t = threadIdx.x;
  unsigned local[16], lsum = 0;
  for (int q = 0; q < 16; ++q) {            // rank r = t*16+q, bin = NBINS-1-r (scan from top)
    local[q] = h[NBINS - 1 - (t * 16 + q)];
    lsum += local[q];
  }
  cs[t] = lsum;
  __syncthreads();
  for (int off = 1; off < 1024; off <<= 1) {  // Hillis-Steele inclusive scan
    unsigned v = (t >= off) ? cs[t - off] : 0u;
    __syncthreads();
    cs[t] += v;
    __syncthreads();
  }
  unsigned incl = cs[t], excl = incl - lsum;
  if (excl < NPOST && incl >= NPOST) {
    unsigned running = excl;
    for (int q = 0; q < 16; ++q) {
      unsigned c = local[q];
      if (running < NPOST && running + c >= NPOST) {
        unsigned bin = NBINS - 1 - (t * 16 + q);
        meta[b] = make_float4(red_m, red_s, __uint_as_float(bin), 0.f);
      }
      running += c;
    }
  }
}

// ---------------- K3: compact + presort segment (first 28 bitonic passes) ----
// Block (b,blk) builds its 128-slot segment in LDS, then runs the bitonic
// network's k=2..128 stages using GLOBAL index directions, so k_sort_emit can
// start at k=256 with bit-identical results.
__global__ __launch_bounds__(256) void k_compact(const float* __restrict__ labels,
                                                 const float4* __restrict__ meta,
                                                 ull* __restrict__ cand) {
  int b = blockIdx.x >> 4, blk = blockIdx.x & 15;
  unsigned tb = __float_as_uint(meta[b].z);
  const int chunk = NA / 16;               // 9216 floats = 2304 float4
  const float4* row4 = (const float4*)(labels + (size_t)b * NA + blk * chunk);
  int tid = threadIdx.x;

  float4 v[9];
#pragma unroll
  for (int it = 0; it < 9; ++it)
    v[it] = row4[it * 256 + tid];

  unsigned c = 0;
#pragma unroll
  for (int it = 0; it < 9; ++it) {
    c += ((mkey(v[it].x) >> 18) >= tb);
    c += ((mkey(v[it].y) >> 18) >= tb);
    c += ((mkey(v[it].z) >> 18) >= tb);
    c += ((mkey(v[it].w) >> 18) >= tb);
  }

  __shared__ unsigned ssum[256];
  __shared__ ull seg[SEG];
  if (tid < SEG) seg[tid] = 0ULL;
  ssum[tid] = c;
  __syncthreads();
  for (int off = 1; off < 256; off <<= 1) {
    unsigned t = (tid >= off) ? ssum[tid - off] : 0u;
    __syncthreads();
    ssum[tid] += t;
    __syncthreads();
  }
  unsigned pos = ssum[tid] - c;            // exclusive prefix

  if (c) {
#pragma unroll
    for (int it = 0; it < 9; ++it) {
      float vals[4] = {v[it].x, v[it].y, v[it].z, v[it].w};
#pragma unroll
      for (int j = 0; j < 4; ++j) {
        unsigned kk = mkey(vals[j]);
        if ((kk >> 18) >= tb) {
          unsigned idx = (unsigned)(blk * chunk + (it * 256 + tid) * 4 + j);
          if (pos < SEG) seg[pos] = ((ull)kk << 32) | (unsigned)~idx;
          pos++;
        }
      }
    }
  }
  __syncthreads();

  // bitonic stages k=2..128, directions from global element index
  int gbase = blk * SEG;
  for (int k = 2; k <= SEG; k <<= 1) {
    for (int j = k >> 1; j > 0; j >>= 1) {
      if (tid < SEG) {
        int e = tid, x = e ^ j;
        if (x > e) {
          ull a = seg[e], cc = seg[x];
          bool up = ((gbase + e) & k) == 0;
          if (up ? (a < cc) : (a > cc)) { seg[e] = cc; seg[x] = a; }
        }
      }
      __syncthreads();
    }
  }

  ull* cb = cand + (size_t)b * CAND_CAP + blk * SEG;
  if (tid < SEG) cb[tid] = seg[tid];
}

// ---------------- K4: bitonic merge stages k=256..2048, emit top-1000 --------
__global__ __launch_bounds__(1024) void k_sort_emit(const ull* __restrict__ cand,
                                                    const float4* __restrict__ meta,
                                                    const float* __restrict__ labels,
                                                    const float* __restrict__ deltas,
                                                    const float4* __restrict__ anchors,
                                                    const float* __restrict__ variances,
                                                    float4* __restrict__ sboxes,
                                                    float* __restrict__ sscores) {
  int b = blockIdx.x;
  __shared__ ull sd[CAND_CAP];
  for (int i = threadIdx.x; i < CAND_CAP; i += 1024)
    sd[i] = cand[(size_t)b * CAND_CAP + i];  // 16 presorted 128-runs

  for (int k = 256; k <= CAND_CAP; k <<= 1) {
    for (int j = k >> 1; j > 0; j >>= 1) {
      __syncthreads();
      for (int e = threadIdx.x; e < CAND_CAP; e += 1024) {
        int x = e ^ j;
        if (x > e) {
          ull a = sd[e], c = sd[x];
          bool up = (e & k) == 0;
          if (up ? (a < c) : (a > c)) { sd[e] = c; sd[x] = a; }
        }
      }
    }
  }
  __syncthreads();

  int r = threadIdx.x;
  if (r < NPOST) {
    ull en = sd[r];
    unsigned idx = ~(unsigned)(en & 0xFFFFFFFFu);
    float4 mt = meta[b];
    float lab = labels[(size_t)b * NA + idx];
    float score = expf(lab - mt.x) / mt.y;

    float4 an = anchors[idx];                     // [y1,x1,y2,x2]
    float aw = an.w - an.y;
    float ah = an.z - an.x;
    float acx = an.y + 0.5f * aw;
    float acy = an.x + 0.5f * ah;
    float4 dl = *(const float4*)(deltas + ((size_t)b * NA + idx) * 4);
    float4 var = *(const float4*)variances;
    float t0 = dl.x * var.x, t1 = dl.y * var.y, t2 = dl.z * var.z, t3 = dl.w * var.w;
    float bw = expf(t3) * aw;
    float bh = expf(t2) * ah;
    float bcx = t1 * aw + acx;
    float bcy = t0 * ah + acy;
    float y1 = bcy - 0.5f * bh, x1 = bcx - 0.5f * bw;
    float y2 = bh + y1, x2 = bw + x1;
    sboxes[(size_t)b * NPOST + r] = make_float4(y1, x1, y2, x2);
    sscores[(size_t)b * NPOST + r] = score;
  }
}

// ---------------- K5: pairwise IoU, TRANSPOSED (lower-tri) bitmask -----------
__global__ __launch_bounds__(256) void k_mask(const float4* __restrict__ sboxes,
                                              ull* __restrict__ maskT) {
  int b = blockIdx.x / 63, tile = blockIdx.x % 63;
  __shared__ float4 bx[NPOST];               // 16KB
  for (int j = threadIdx.x; j < NPOST; j += 256) bx[j] = sboxes[(size_t)b * NPOST + j];
  __syncthreads();
  int il = threadIdx.x >> 4, w = threadIdx.x & 15;
  int i = tile * 16 + il;
  if (i < NPOST) {
    float4 bi = bx[i];
    float ay1 = bi.x, ax1 = bi.y, ay2 = bi.z, ax2 = bi.w;
    float areai = (ay2 - ay1) * (ax2 - ax1);
    ull bits = 0;
    for (int jj = 0; jj < 64; ++jj) {
      int jb = (jj + w) & 63;                // skew to dodge LDS bank conflicts
      int j = (w << 6) + jb;
      if (j < i) {                           // lower-tri: rows j that suppress col i
        float4 bj = bx[j];
        float areaj = (bj.z - bj.x) * (bj.w - bj.y);
        float iy1 = fmaxf(ay1, bj.x), ix1 = fmaxf(ax1, bj.y);
        float iy2 = fminf(ay2, bj.z), ix2 = fminf(ax2, bj.w);
        float inter = fmaxf(iy2 - iy1, 0.f) * fmaxf(ix2 - ix1, 0.f);
        float uni = areai + areaj - inter;
        float iou = inter / fmaxf(uni, 1e-9f);
        if (iou > 0.7f) bits |= (1ull << jb);
      }
    }
    maskT[((size_t)b * NPOST + i) * 16 + w] = bits;
  }
}

// ---------------- K6: greedy NMS on transposed mask --------------------------
// launch_bounds(256,1): full VGPR budget so cur[16]+nxt[16] stay in registers.
// keep[] cached in wave-uniform scalars (switch-assigned), acc statically
// unrolled -> no LDS on the phase-serial path.
__global__ __launch_bounds__(256, 1) void k_nms(const ull* __restrict__ maskT,
                                                const float4* __restrict__ sboxes,
                                                const float* __restrict__ sscores,
                                                float* __restrict__ out) {
  int b = blockIdx.x;
  __shared__ ull keep_lds[16];
  __shared__ int pref[17];
  int tid = threadIdx.x;

  if (tid < 64) {
    int lane = tid;
    const ull* MT = maskT + (size_t)b * NPOST * 16;

    ull cur[16];
#pragma unroll
    for (int k = 0; k < 16; ++k) cur[k] = MT[(size_t)lane * 16 + k];
    ull qT = cur[0];

    ull ks0=0,ks1=0,ks2=0,ks3=0,ks4=0,ks5=0,ks6=0,ks7=0,
        ks8=0,ks9=0,ks10=0,ks11=0,ks12=0,ks13=0,ks14=0;   // ks15 never read

#pragma unroll 1
    for (int w = 0; w < 16; ++w) {
      // prefetch next phase's column words (clamped row; garbage is unused)
      ull nxt[16]; ull qTn;
      int nr = (w + 1) * 64 + lane; if (nr > NPOST - 1) nr = NPOST - 1;
      int nw = w + 1 < 15 ? w + 1 : 15;
#pragma unroll
      for (int k = 0; k < 16; ++k) nxt[k] = MT[(size_t)nr * 16 + k];
      qTn = MT[(size_t)nr * 16 + nw];

      // cross-word suppression: uniform keep scalars, per-lane columns
      ull acc = (cur[0]&ks0)|(cur[1]&ks1)|(cur[2]&ks2)|(cur[3]&ks3)
              |(cur[4]&ks4)|(cur[5]&ks5)|(cur[6]&ks6)|(cur[7]&ks7)
              |(cur[8]&ks8)|(cur[9]&ks9)|(cur[10]&ks10)|(cur[11]&ks11)
              |(cur[12]&ks12)|(cur[13]&ks13)|(cur[14]&ks14);
      ull rm0 = __ballot(acc != 0ull);

      // in-word serial chain (SALU), 16 columns per marshal batch
      ull kmask = 0;
#pragma unroll 1
      for (int cb = 0; cb < 4; ++cb) {
        ull cols[16];
#pragma unroll
        for (int c = 0; c < 16; ++c) cols[c] = readlane64(qT, cb * 16 + c);
#pragma unroll
        for (int c = 0; c < 16; ++c) {
          int cc = cb * 16 + c;
          bool kp = (((rm0 >> cc) & 1ull) == 0ull) && ((cols[c] & kmask) == 0ull);
          kmask |= kp ? (1ull << cc) : 0ull;
        }
      }
      if (w == 15) kmask &= (1ull << 40) - 1;   // boxes 1000..1023 invalid
      if (lane == 0) keep_lds[w] = kmask;
      switch (w) {
        case 0:  ks0  = kmask; break;  case 1:  ks1  = kmask; break;
        case 2:  ks2  = kmask; break;  case 3:  ks3  = kmask; break;
        case 4:  ks4  = kmask; break;  case 5:  ks5  = kmask; break;
        case 6:  ks6  = kmask; break;  case 7:  ks7  = kmask; break;
        case 8:  ks8  = kmask; break;  case 9:  ks9  = kmask; break;
        case 10: ks10 = kmask; break;  case 11: ks11 = kmask; break;
        case 12: ks12 = kmask; break;  case 13: ks13 = kmask; break;
        case 14: ks14 = kmask; break;  default: break;
      }

#pragma unroll
      for (int k = 0; k < 16; ++k) cur[k] = nxt[k];
      qT = qTn;
    }

    if (lane == 0) {
      int a = 0;
      for (int w = 0; w < 16; ++w) { pref[w] = a; a += __popcll(keep_lds[w]); }
      pref[16] = a;
    }
  }
  __syncthreads();

  int total = pref[16];
  float4* ob = (float4*)out;                 // boxes: 16*1000 float4
  float* os = out + (size_t)NB * NPOST * 4;  // scores: 16*1000 floats
  for (int r = tid; r < NPOST; r += 256) {
    if (r >= total) {
      ob[(size_t)b * NPOST + r] = make_float4(0.f, 0.f, 0.f, 0.f);
      os[(size_t)b * NPOST + r] = 0.f;
    }
  }
  for (int r = tid; r < NPOST; r += 256) {
    int w = r >> 6, bb = r & 63;
    ull kw = keep_lds[w];
    if ((kw >> bb) & 1ull) {
      int pos = pref[w] + __popcll(bb ? (kw & ((1ull << bb) - 1)) : 0ull);
      ob[(size_t)b * NPOST + pos] = sboxes[(size_t)b * NPOST + r];
      os[(size_t)b * NPOST + pos] = sscores[(size_t)b * NPOST + r];
    }
  }
}

extern "C" void kernel_launch(void* const* d_in, const int* in_sizes, int n_in,
                              void* d_out, int out_size, void* d_ws, size_t ws_size,
                              hipStream_t stream) {
  const float* deltas    = (const float*)d_in[0];
  const float* labels    = (const float*)d_in[1];
  const float* anchors   = (const float*)d_in[2];
  const float* variances = (const float*)d_in[3];

  char* ws = (char*)d_ws;
  ull*      cand    = (ull*)(ws + OFF_CAND);
  ull*      maskT   = (ull*)(ws + OFF_MASK);
  unsigned* hist    = (unsigned*)(ws + OFF_HIST);
  float2*   partial = (float2*)(ws + OFF_PART);
  float4*   meta    = (float4*)(ws + OFF_META);
  float4*   sboxes  = (float4*)(ws + OFF_SBOX);
  float*    sscores = (float*)(ws + OFF_SSCORE);

  k_init<<<256, 256, 0, stream>>>(hist);
  k_reduce_hist<<<NB * 16, 256, 0, stream>>>(labels, hist, partial);
  k_threshold<<<NB, 1024, 0, stream>>>(hist, partial, meta);
  k_compact<<<NB * 16, 256, 0, stream>>>(labels, meta, cand);
  k_sort_emit<<<NB, 1024, 0, stream>>>(cand, meta, labels, deltas,
                                       (const float4*)anchors, variances,
                                       sboxes, sscores);
  k_mask<<<NB * 63, 256, 0, stream>>>(sboxes, maskT);
  k_nms<<<NB, 256, 0, stream>>>(maskT, sboxes, sscores, (float*)d_out);
}

// Round 9
// 111.186 us; speedup vs baseline: 2.7388x; 1.0854x over previous
//
#include <hip/hip_runtime.h>

typedef unsigned long long ull;

#define NA 147456
#define NB 16
#define NBINS 16384        // top-14 bits of monotonic key
#define CAND_CAP 2048
#define SEG 128            // CAND_CAP / 16 chunks
#define NPOST 1000

// ws layout (bytes)
#define OFF_CAND    0                    // 16*2048*8      = 262144
#define OFF_MASK    262144               // 16*1000*16*8   = 2048000 (maskT)
#define OFF_HIST    2310144              // 16*16384*4     = 1048576
#define OFF_PART    3358720              // 16*16*8        = 2048
#define OFF_META    3360768              // 16*16          = 256
#define OFF_SBOX    3361088              // 16*1000*16     = 256000
#define OFF_SSCORE  3617088              // 16*1000*4      = 64000

__device__ __forceinline__ unsigned mkey(float f) {
  unsigned u = __float_as_uint(f);
  return u ^ ((unsigned)((int)u >> 31) | 0x80000000u);  // monotonic: bigger float -> bigger key
}

// ---------------- K0: zero hist (ws is poisoned 0xAA) ------------------------
__global__ void k_init(unsigned* hist) {
  int n = NB * NBINS;
  for (int i = blockIdx.x * blockDim.x + threadIdx.x; i < n; i += gridDim.x * blockDim.x)
    hist[i] = 0;
}

// ---------------- K1: fused online softmax-reduce + 14-bit histogram ---------
__global__ __launch_bounds__(256) void k_reduce_hist(const float* __restrict__ labels,
                                                     unsigned* __restrict__ hist,
                                                     float2* __restrict__ partial) {
  int b = blockIdx.x >> 4, blk = blockIdx.x & 15;
  __shared__ unsigned lh[NBINS];           // 64KB
  __shared__ float rm[256], rs[256];
  for (int i = threadIdx.x; i < NBINS; i += 256) lh[i] = 0;
  __syncthreads();

  const float* row = labels + (size_t)b * NA;
  const int chunk = NA / 16;               // 9216, divisible by 256
  int base = blk * chunk;
  float m = -INFINITY, s = 0.f;
  for (int i = threadIdx.x; i < chunk; i += 256) {
    float v = row[base + i];
    atomicAdd(&lh[mkey(v) >> 18], 1u);
    if (v > m) { s = s * expf(m - v) + 1.f; m = v; }
    else       { s += expf(v - m); }
  }
  rm[threadIdx.x] = m; rs[threadIdx.x] = s;
  __syncthreads();
  for (int off = 128; off > 0; off >>= 1) {
    if (threadIdx.x < off) {
      float m1 = rm[threadIdx.x], s1 = rs[threadIdx.x];
      float m2 = rm[threadIdx.x + off], s2 = rs[threadIdx.x + off];
      float M = fmaxf(m1, m2);
      rm[threadIdx.x] = M;
      rs[threadIdx.x] = s1 * expf(m1 - M) + s2 * expf(m2 - M);
    }
    __syncthreads();
  }
  if (threadIdx.x == 0) partial[blockIdx.x] = make_float2(rm[0], rs[0]);
  for (int i = threadIdx.x; i < NBINS; i += 256) {
    unsigned c = lh[i];
    if (c) atomicAdd(&hist[b * NBINS + i], c);
  }
}

// ---------------- K2: finalize (m,S), find threshold bin ---------------------
__global__ __launch_bounds__(1024) void k_threshold(const unsigned* __restrict__ hist,
                                                    const float2* __restrict__ partial,
                                                    float4* __restrict__ meta) {
  int b = blockIdx.x;
  __shared__ float red_m, red_s;
  __shared__ unsigned cs[1024];
  if (threadIdx.x == 0) {
    float m = -INFINITY, s = 0.f;
    for (int i = 0; i < 16; ++i) {
      float2 p = partial[b * 16 + i];
      float M = fmaxf(m, p.x);
      s = s * expf(m - M) + p.y * expf(p.x - M);
      m = M;
    }
    red_m = m; red_s = s;
  }
  const unsigned* h = hist + (size_t)b * NBINS;
  int t = threadIdx.x;
  unsigned local[16], lsum = 0;
  for (int q = 0; q < 16; ++q) {            // rank r = t*16+q, bin = NBINS-1-r (scan from top)
    local[q] = h[NBINS - 1 - (t * 16 + q)];
    lsum += local[q];
  }
  cs[t] = lsum;
  __syncthreads();
  for (int off = 1; off < 1024; off <<= 1) {  // Hillis-Steele inclusive scan
    unsigned v = (t >= off) ? cs[t - off] : 0u;
    __syncthreads();
    cs[t] += v;
    __syncthreads();
  }
  unsigned incl = cs[t], excl = incl - lsum;
  if (excl < NPOST && incl >= NPOST) {
    unsigned running = excl;
    for (int q = 0; q < 16; ++q) {
      unsigned c = local[q];
      if (running < NPOST && running + c >= NPOST) {
        unsigned bin = NBINS - 1 - (t * 16 + q);
        meta[b] = make_float4(red_m, red_s, __uint_as_float(bin), 0.f);
      }
      running += c;
    }
  }
}

// ---------------- K3: compact + presort segment (first 28 bitonic passes) ----
__global__ __launch_bounds__(256) void k_compact(const float* __restrict__ labels,
                                                 const float4* __restrict__ meta,
                                                 ull* __restrict__ cand) {
  int b = blockIdx.x >> 4, blk = blockIdx.x & 15;
  unsigned tb = __float_as_uint(meta[b].z);
  const int chunk = NA / 16;               // 9216 floats = 2304 float4
  const float4* row4 = (const float4*)(labels + (size_t)b * NA + blk * chunk);
  int tid = threadIdx.x;

  float4 v[9];
#pragma unroll
  for (int it = 0; it < 9; ++it)
    v[it] = row4[it * 256 + tid];

  unsigned c = 0;
#pragma unroll
  for (int it = 0; it < 9; ++it) {
    c += ((mkey(v[it].x) >> 18) >= tb);
    c += ((mkey(v[it].y) >> 18) >= tb);
    c += ((mkey(v[it].z) >> 18) >= tb);
    c += ((mkey(v[it].w) >> 18) >= tb);
  }

  __shared__ unsigned ssum[256];
  __shared__ ull seg[SEG];
  if (tid < SEG) seg[tid] = 0ULL;
  ssum[tid] = c;
  __syncthreads();
  for (int off = 1; off < 256; off <<= 1) {
    unsigned t = (tid >= off) ? ssum[tid - off] : 0u;
    __syncthreads();
    ssum[tid] += t;
    __syncthreads();
  }
  unsigned pos = ssum[tid] - c;            // exclusive prefix

  if (c) {
#pragma unroll
    for (int it = 0; it < 9; ++it) {
      float vals[4] = {v[it].x, v[it].y, v[it].z, v[it].w};
#pragma unroll
      for (int j = 0; j < 4; ++j) {
        unsigned kk = mkey(vals[j]);
        if ((kk >> 18) >= tb) {
          unsigned idx = (unsigned)(blk * chunk + (it * 256 + tid) * 4 + j);
          if (pos < SEG) seg[pos] = ((ull)kk << 32) | (unsigned)~idx;
          pos++;
        }
      }
    }
  }
  __syncthreads();

  // bitonic stages k=2..128, directions from global element index
  int gbase = blk * SEG;
  for (int k = 2; k <= SEG; k <<= 1) {
    for (int j = k >> 1; j > 0; j >>= 1) {
      if (tid < SEG) {
        int e = tid, x = e ^ j;
        if (x > e) {
          ull a = seg[e], cc = seg[x];
          bool up = ((gbase + e) & k) == 0;
          if (up ? (a < cc) : (a > cc)) { seg[e] = cc; seg[x] = a; }
        }
      }
      __syncthreads();
    }
  }

  ull* cb = cand + (size_t)b * CAND_CAP + blk * SEG;
  if (tid < SEG) cb[tid] = seg[tid];
}

// ---------------- K4: bitonic merge stages k=256..2048, emit top-1000 --------
__global__ __launch_bounds__(1024) void k_sort_emit(const ull* __restrict__ cand,
                                                    const float4* __restrict__ meta,
                                                    const float* __restrict__ labels,
                                                    const float* __restrict__ deltas,
                                                    const float4* __restrict__ anchors,
                                                    const float* __restrict__ variances,
                                                    float4* __restrict__ sboxes,
                                                    float* __restrict__ sscores) {
  int b = blockIdx.x;
  __shared__ ull sd[CAND_CAP];
  for (int i = threadIdx.x; i < CAND_CAP; i += 1024)
    sd[i] = cand[(size_t)b * CAND_CAP + i];  // 16 presorted 128-runs

  for (int k = 256; k <= CAND_CAP; k <<= 1) {
    for (int j = k >> 1; j > 0; j >>= 1) {
      __syncthreads();
      for (int e = threadIdx.x; e < CAND_CAP; e += 1024) {
        int x = e ^ j;
        if (x > e) {
          ull a = sd[e], c = sd[x];
          bool up = (e & k) == 0;
          if (up ? (a < c) : (a > c)) { sd[e] = c; sd[x] = a; }
        }
      }
    }
  }
  __syncthreads();

  int r = threadIdx.x;
  if (r < NPOST) {
    ull en = sd[r];
    unsigned idx = ~(unsigned)(en & 0xFFFFFFFFu);
    float4 mt = meta[b];
    float lab = labels[(size_t)b * NA + idx];
    float score = expf(lab - mt.x) / mt.y;

    float4 an = anchors[idx];                     // [y1,x1,y2,x2]
    float aw = an.w - an.y;
    float ah = an.z - an.x;
    float acx = an.y + 0.5f * aw;
    float acy = an.x + 0.5f * ah;
    float4 dl = *(const float4*)(deltas + ((size_t)b * NA + idx) * 4);
    float4 var = *(const float4*)variances;
    float t0 = dl.x * var.x, t1 = dl.y * var.y, t2 = dl.z * var.z, t3 = dl.w * var.w;
    float bw = expf(t3) * aw;
    float bh = expf(t2) * ah;
    float bcx = t1 * aw + acx;
    float bcy = t0 * ah + acy;
    float y1 = bcy - 0.5f * bh, x1 = bcx - 0.5f * bw;
    float y2 = bh + y1, x2 = bw + x1;
    sboxes[(size_t)b * NPOST + r] = make_float4(y1, x1, y2, x2);
    sscores[(size_t)b * NPOST + r] = score;
  }
}

// ---------------- K5: pairwise IoU, TRANSPOSED (lower-tri) bitmask -----------
__global__ __launch_bounds__(256) void k_mask(const float4* __restrict__ sboxes,
                                              ull* __restrict__ maskT) {
  int b = blockIdx.x / 63, tile = blockIdx.x % 63;
  __shared__ float4 bx[NPOST];               // 16KB
  for (int j = threadIdx.x; j < NPOST; j += 256) bx[j] = sboxes[(size_t)b * NPOST + j];
  __syncthreads();
  int il = threadIdx.x >> 4, w = threadIdx.x & 15;
  int i = tile * 16 + il;
  if (i < NPOST) {
    float4 bi = bx[i];
    float ay1 = bi.x, ax1 = bi.y, ay2 = bi.z, ax2 = bi.w;
    float areai = (ay2 - ay1) * (ax2 - ax1);
    ull bits = 0;
    for (int jj = 0; jj < 64; ++jj) {
      int jb = (jj + w) & 63;                // skew to dodge LDS bank conflicts
      int j = (w << 6) + jb;
      if (j < i) {                           // lower-tri: rows j that suppress col i
        float4 bj = bx[j];
        float areaj = (bj.z - bj.x) * (bj.w - bj.y);
        float iy1 = fmaxf(ay1, bj.x), ix1 = fmaxf(ax1, bj.y);
        float iy2 = fminf(ay2, bj.z), ix2 = fminf(ax2, bj.w);
        float inter = fmaxf(iy2 - iy1, 0.f) * fmaxf(ix2 - ix1, 0.f);
        float uni = areai + areaj - inter;
        float iou = inter / fmaxf(uni, 1e-9f);
        if (iou > 0.7f) bits |= (1ull << jb);
      }
    }
    maskT[((size_t)b * NPOST + i) * 16 + w] = bits;
  }
}

// ---------------- K6: greedy NMS, fully unrolled, ballot-row chain -----------
// Fully unrolled 16 phases -> every array index static -> all state in regs.
// Phase w: lane c holds column (w*64+c)'s words 0..w (lower-tri: rest zero).
//   rm0  = ballot(OR_{k<w}(colw[k] & ks[k]) != 0)   (cross-word suppression)
//   rows[r] = ballot(bit r of diagonal word)        (in-word, lands in SGPRs)
//   64-step keep chain on wave-uniform values -> SALU.
__global__ __launch_bounds__(256, 1) void k_nms(const ull* __restrict__ maskT,
                                                const float4* __restrict__ sboxes,
                                                const float* __restrict__ sscores,
                                                float* __restrict__ out) {
  int b = blockIdx.x;
  __shared__ ull keep_lds[16];
  __shared__ int pref[17];
  int tid = threadIdx.x;

  if (tid < 64) {
    int lane = tid;
    const ull* MT = maskT + (size_t)b * NPOST * 16;

    ull colw[16], coln[16], ks[16];
#pragma unroll
    for (int k = 0; k < 16; ++k) { colw[k] = 0; coln[k] = 0; ks[k] = 0; }
    colw[0] = MT[(size_t)lane * 16 + 0];

#pragma unroll
    for (int w = 0; w < 16; ++w) {
      // prefetch phase w+1: words 0..w+1 of column ((w+1)*64+lane)
      if (w < 15) {
        int nr = (w + 1) * 64 + lane; if (nr > NPOST - 1) nr = NPOST - 1;
#pragma unroll
        for (int k = 0; k < 16; ++k)
          if (k <= w + 1) coln[k] = MT[(size_t)nr * 16 + k];
      }

      // cross-word suppression (words k<w; uniform ks in SGPR, colw in VGPR)
      ull acc = 0;
#pragma unroll
      for (int k = 0; k < 16; ++k)
        if (k < w) acc |= colw[k] & ks[k];
      ull rm0 = (w == 0) ? 0ull : __ballot(acc != 0ull);

      unsigned qlo = (unsigned)colw[w], qhi = (unsigned)(colw[w] >> 32);

      ull kmask = 0, supp = rm0;
#pragma unroll
      for (int bt = 0; bt < 4; ++bt) {
        ull rows[16];
        unsigned qd = (bt < 2) ? qlo : qhi;
#pragma unroll
        for (int r = 0; r < 16; ++r)
          rows[r] = __ballot(((qd >> ((bt & 1) * 16 + r)) & 1u) != 0u);
#pragma unroll
        for (int r = 0; r < 16; ++r) {
          int rr = bt * 16 + r;
          bool kp = ((supp >> rr) & 1ull) == 0ull;
          kmask |= kp ? (1ull << rr) : 0ull;
          supp  |= kp ? rows[r] : 0ull;
        }
      }
      if (w == 15) kmask &= (1ull << 40) - 1;   // boxes 1000..1023 invalid
      ks[w] = kmask;
      if (lane == 0) keep_lds[w] = kmask;

#pragma unroll
      for (int k = 0; k < 16; ++k) colw[k] = coln[k];
    }

    if (lane == 0) {
      int a = 0;
      for (int w = 0; w < 16; ++w) { pref[w] = a; a += __popcll(keep_lds[w]); }
      pref[16] = a;
    }
  }
  __syncthreads();

  int total = pref[16];
  float4* ob = (float4*)out;                 // boxes: 16*1000 float4
  float* os = out + (size_t)NB * NPOST * 4;  // scores: 16*1000 floats
  for (int r = tid; r < NPOST; r += 256) {
    if (r >= total) {
      ob[(size_t)b * NPOST + r] = make_float4(0.f, 0.f, 0.f, 0.f);
      os[(size_t)b * NPOST + r] = 0.f;
    }
  }
  for (int r = tid; r < NPOST; r += 256) {
    int w = r >> 6, bb = r & 63;
    ull kw = keep_lds[w];
    if ((kw >> bb) & 1ull) {
      int pos = pref[w] + __popcll(bb ? (kw & ((1ull << bb) - 1)) : 0ull);
      ob[(size_t)b * NPOST + pos] = sboxes[(size_t)b * NPOST + r];
      os[(size_t)b * NPOST + pos] = sscores[(size_t)b * NPOST + r];
    }
  }
}

extern "C" void kernel_launch(void* const* d_in, const int* in_sizes, int n_in,
                              void* d_out, int out_size, void* d_ws, size_t ws_size,
                              hipStream_t stream) {
  const float* deltas    = (const float*)d_in[0];
  const float* labels    = (const float*)d_in[1];
  const float* anchors   = (const float*)d_in[2];
  const float* variances = (const float*)d_in[3];

  char* ws = (char*)d_ws;
  ull*      cand    = (ull*)(ws + OFF_CAND);
  ull*      maskT   = (ull*)(ws + OFF_MASK);
  unsigned* hist    = (unsigned*)(ws + OFF_HIST);
  float2*   partial = (float2*)(ws + OFF_PART);
  float4*   meta    = (float4*)(ws + OFF_META);
  float4*   sboxes  = (float4*)(ws + OFF_SBOX);
  float*    sscores = (float*)(ws + OFF_SSCORE);

  k_init<<<256, 256, 0, stream>>>(hist);
  k_reduce_hist<<<NB * 16, 256, 0, stream>>>(labels, hist, partial);
  k_threshold<<<NB, 1024, 0, stream>>>(hist, partial, meta);
  k_compact<<<NB * 16, 256, 0, stream>>>(labels, meta, cand);
  k_sort_emit<<<NB, 1024, 0, stream>>>(cand, meta, labels, deltas,
                                       (const float4*)anchors, variances,
                                       sboxes, sscores);
  k_mask<<<NB * 63, 256, 0, stream>>>(sboxes, maskT);
  k_nms<<<NB, 256, 0, stream>>>(maskT, sboxes, sscores, (float*)d_out);
}